// Round 2
// baseline (546.192 us; speedup 1.0000x reference)
//
#include <hip/hip_runtime.h>
#include <stdint.h>
#include <stddef.h>

// Problem constants
#define BB 2
#define TT 4096
#define EE 768
#define HH 12
#define DH 64
#define WW 256
#define NCHUNK 16
#define GG 16

typedef __bf16 bf16_t;
typedef __bf16 bf16x8 __attribute__((ext_vector_type(8)));
typedef float f32x4 __attribute__((ext_vector_type(4)));

__device__ inline f32x4 mfma16(bf16x8 a, bf16x8 b, f32x4 c) {
    return __builtin_amdgcn_mfma_f32_16x16x32_bf16(a, b, c, 0, 0, 0);
}

// ---------------- prep: x (fp32) -> xb (bf16) ----------------
__global__ __launch_bounds__(256) void k_prep_x(const float* __restrict__ x,
                                                bf16_t* __restrict__ xb) {
    const int i = (blockIdx.x * 256 + threadIdx.x) * 8;
    f32x4 a = *(const f32x4*)(x + i);
    f32x4 b = *(const f32x4*)(x + i + 4);
    bf16x8 o;
    o[0] = (bf16_t)a[0]; o[1] = (bf16_t)a[1]; o[2] = (bf16_t)a[2]; o[3] = (bf16_t)a[3];
    o[4] = (bf16_t)b[0]; o[5] = (bf16_t)b[1]; o[6] = (bf16_t)b[2]; o[7] = (bf16_t)b[3];
    *(bf16x8*)(xb + i) = o;
}

// ---------------- prep: W (fp32, K x N) -> Wt (bf16, N x K), 5 weights ----------------
__global__ __launch_bounds__(256) void k_prep_w(const float* __restrict__ w0,
                                                const float* __restrict__ w1,
                                                const float* __restrict__ w2,
                                                const float* __restrict__ w3,
                                                const float* __restrict__ w4,
                                                bf16_t* __restrict__ wt) {
    const int z = blockIdx.z;
    const float* W = (z == 0) ? w0 : (z == 1) ? w1 : (z == 2) ? w2 : (z == 3) ? w3 : w4;
    const int k0 = blockIdx.x * 64;
    const int n0 = blockIdx.y * 64;
    const int tid = threadIdx.x;
    __shared__ __align__(16) bf16_t ls[64 * 65];
    #pragma unroll
    for (int i = 0; i < 16; ++i) {
        int idx = i * 256 + tid;
        int kr = idx >> 6, nc = idx & 63;
        ls[nc * 65 + kr] = (bf16_t)W[(size_t)(k0 + kr) * EE + n0 + nc];
    }
    __syncthreads();
    bf16_t* o = wt + (size_t)z * EE * EE;
    #pragma unroll
    for (int i = 0; i < 16; ++i) {
        int idx = i * 256 + tid;
        int nr = idx >> 6, kc = idx & 63;
        o[(size_t)(n0 + nr) * EE + k0 + kc] = ls[nr * 65 + kc];
    }
}

// ---------------- projection GEMM: proj[z] = xb @ W[z] + b[z]  (bf16 MFMA) --------------
// out layout: (B,H,T,Dh) bf16; z: 0=q(scaled 1/8) 1=k 2=v 3=kgl 4=vgl
__global__ __launch_bounds__(256) void k_gemm(const bf16_t* __restrict__ xb,
                                              const bf16_t* __restrict__ wt,
                                              const float* __restrict__ b0,
                                              const float* __restrict__ b1,
                                              const float* __restrict__ b2,
                                              const float* __restrict__ b3,
                                              const float* __restrict__ b4,
                                              bf16_t* __restrict__ proj) {
    const int tid = threadIdx.x;
    const int z = blockIdx.z;
    const int m0 = blockIdx.x * 128;
    const int n0 = blockIdx.y * 128;
    const float* bias = (z == 0) ? b0 : (z == 1) ? b1 : (z == 2) ? b2 : (z == 3) ? b3 : b4;
    const float scale = (z == 0) ? 0.125f : 1.0f;
    const bf16_t* wz = wt + (size_t)z * EE * EE;
    bf16_t* dst = proj + (size_t)z * BB * HH * TT * DH;

    __shared__ __align__(16) bf16_t lA[128 * 72];
    __shared__ __align__(16) bf16_t lB[128 * 72];

    const int lane = tid & 63, wid = tid >> 6;
    const int wr = wid >> 1, wc = wid & 1;
    const int lg = lane >> 4, lr = lane & 15;

    f32x4 acc[4][4];
    const f32x4 z4 = {0.f, 0.f, 0.f, 0.f};
    #pragma unroll
    for (int i = 0; i < 4; ++i)
        #pragma unroll
        for (int j = 0; j < 4; ++j) acc[i][j] = z4;

    for (int kt = 0; kt < 12; ++kt) {
        const int k0 = kt * 64;
        #pragma unroll
        for (int it = 0; it < 4; ++it) {
            int q = it * 256 + tid;       // 0..1023
            int row = q >> 3;             // 0..127
            int c8 = (q & 7) * 8;         // 0..56
            f32x4 av = *(const f32x4*)(xb + (size_t)(m0 + row) * EE + k0 + c8);
            *(f32x4*)(&lA[row * 72 + c8]) = av;
            f32x4 bv = *(const f32x4*)(wz + (size_t)(n0 + row) * EE + k0 + c8);
            *(f32x4*)(&lB[row * 72 + c8]) = bv;
        }
        __syncthreads();
        #pragma unroll
        for (int kk = 0; kk < 2; ++kk) {
            bf16x8 af[4], bfr[4];
            #pragma unroll
            for (int mi = 0; mi < 4; ++mi)
                af[mi] = *(const bf16x8*)(&lA[(wr * 64 + mi * 16 + lr) * 72 + kk * 32 + lg * 8]);
            #pragma unroll
            for (int ni = 0; ni < 4; ++ni)
                bfr[ni] = *(const bf16x8*)(&lB[(wc * 64 + ni * 16 + lr) * 72 + kk * 32 + lg * 8]);
            #pragma unroll
            for (int mi = 0; mi < 4; ++mi)
                #pragma unroll
                for (int ni = 0; ni < 4; ++ni)
                    acc[mi][ni] = mfma16(af[mi], bfr[ni], acc[mi][ni]);
        }
        __syncthreads();
    }

    #pragma unroll
    for (int mi = 0; mi < 4; ++mi)
        #pragma unroll
        for (int ni = 0; ni < 4; ++ni) {
            int n = n0 + wc * 64 + ni * 16 + lr;
            float bn = bias[n];
            int h = n >> 6, d = n & 63;
            #pragma unroll
            for (int r = 0; r < 4; ++r) {
                int m = m0 + wr * 64 + mi * 16 + lg * 4 + r;
                float v = (acc[mi][ni][r] + bn) * scale;
                int bb = m >> 12, t = m & 4095;
                dst[(((size_t)bb * HH + h) * TT + t) * DH + d] = (bf16_t)v;
            }
        }
}

// ---------------- transpose v: (B,H,T,Dh) -> (B,H,Dh,T) bf16 ----------------
__global__ __launch_bounds__(256) void k_tv(const bf16_t* __restrict__ v,
                                            bf16_t* __restrict__ vT) {
    __shared__ __align__(16) bf16_t ls[64 * 65];
    const int t0 = blockIdx.x * 64;
    const int bh = blockIdx.y;
    const int tid = threadIdx.x;
    const bf16_t* vp = v + ((size_t)bh * TT + t0) * DH;
    #pragma unroll
    for (int i = 0; i < 16; ++i) {
        int idx = i * 256 + tid;
        int tr = idx >> 6, dc = idx & 63;
        ls[dc * 65 + tr] = vp[(size_t)tr * DH + dc];
    }
    __syncthreads();
    bf16_t* op = vT + (size_t)bh * DH * TT + t0;
    #pragma unroll
    for (int i = 0; i < 16; ++i) {
        int idx = i * 256 + tid;
        int dr = idx >> 6, tc = idx & 63;
        op[(size_t)dr * TT + tc] = ls[dr * 65 + tc];
    }
}

// ---------------- qg projection: qg = (x[global] @ Wqg + bqg) * 1/8, fp32 ----------------
// out: (B,H,G,Dh) fp32
__global__ __launch_bounds__(256) void k_qg(const float* __restrict__ x,
                                            const float* __restrict__ Wqg,
                                            const float* __restrict__ bqg,
                                            float* __restrict__ qg) {
    const int g = blockIdx.x, b = blockIdx.y;
    const int tid = threadIdx.x;
    __shared__ float xr[EE];
    const float* xrow = x + ((size_t)b * TT + g * WW) * EE;
    for (int i = tid; i < EE; i += 256) xr[i] = xrow[i];
    __syncthreads();
    float a0 = bqg[tid], a1 = bqg[tid + 256], a2 = bqg[tid + 512];
    for (int e = 0; e < EE; ++e) {
        float xe = xr[e];
        const float* wrow = Wqg + (size_t)e * EE;
        a0 += xe * wrow[tid];
        a1 += xe * wrow[tid + 256];
        a2 += xe * wrow[tid + 512];
    }
    float accs[3] = {a0, a1, a2};
    #pragma unroll
    for (int j = 0; j < 3; ++j) {
        int n = tid + j * 256;
        int h = n >> 6, d = n & 63;
        qg[(((size_t)b * HH + h) * GG + g) * DH + d] = accs[j] * 0.125f;
    }
}

// ---------------- local (windowed + global-col) attention ----------------
// 1 wave per block; block handles 64 query rows of one (b,h,chunk,quarter).
// Rewritten: unified LDS-staged global tile + one-row-per-lane softmax through
// an fp32 S_lds roundtrip (no shfl reductions, no special-cased fragments).
__global__ __launch_bounds__(64) void k_lattn(const bf16_t* __restrict__ qs,
                                              const bf16_t* __restrict__ ks,
                                              const bf16_t* __restrict__ vT,
                                              float* __restrict__ out) {
    const int gx = blockIdx.x;
    const int q4 = gx & 3;
    const int c = (gx >> 2) & 15;
    const int bh = gx >> 6;          // 0..23
    const int b = bh / HH, h = bh % HH;
    const int lane = threadIdx.x, lg = lane >> 4, lr = lane & 15;

    const bf16_t* qp = qs + ((size_t)bh * TT + c * WW + q4 * 64) * DH;
    const bf16_t* kp = ks + (size_t)bh * TT * DH;
    const bf16_t* vp = vT + (size_t)bh * DH * TT;

    __shared__ __align__(16) float  S_lds[64 * 65];
    __shared__ __align__(16) bf16_t P[64 * 72];
    __shared__ __align__(16) bf16_t Kg[64 * 72];    // rows 0..15 = global keys, rest 0
    __shared__ __align__(16) bf16_t VgT[64 * 72];   // [d][g]; cols 16..63 = 0
    __shared__ float scr_lds[64];
    __shared__ float linv_lds[64];

    // stage zero-padded global K / V^T tiles (lane = d index)
    for (int r = 0; r < 64; ++r) {
        Kg[r * 72 + lane]  = (r < 16) ? kp[(size_t)r * WW * DH + lane] : (bf16_t)0.f;
        VgT[lane * 72 + r] = (r < 16) ? vp[(size_t)lane * TT + r * WW] : (bf16_t)0.f;
    }

    // Q fragments (A operand): row = lr (+16*mi), k = lg*8 (+32*kk)
    bf16x8 Qf[4][2];
    #pragma unroll
    for (int mi = 0; mi < 4; ++mi)
        #pragma unroll
        for (int kk = 0; kk < 2; ++kk)
            Qf[mi][kk] = *(const bf16x8*)(qp + (size_t)(mi * 16 + lr) * DH + kk * 32 + lg * 8);

    f32x4 O[4][4];
    const f32x4 z4 = {0.f, 0.f, 0.f, 0.f};
    #pragma unroll
    for (int i = 0; i < 4; ++i)
        #pragma unroll
        for (int j = 0; j < 4; ++j) O[i][j] = z4;

    float m_own = -1e30f, l_own = 0.f;   // lane owns query row == lane

    __syncthreads();   // staging visible

    for (int ts = 0; ts < 10; ++ts) {
        const bool isg = (ts == 0);
        const int jt = q4 + ts - 1;
        const int ttile = 4 * (c - 1) + jt;   // global 64-key tile index
        if (!isg && (ttile < 0 || ttile > 63)) continue;

        // K fragments (B operand): col = lr (+16*ni) = key, k = d
        bf16x8 kf[4][2];
        if (isg) {
            #pragma unroll
            for (int ni = 0; ni < 4; ++ni)
                #pragma unroll
                for (int kk = 0; kk < 2; ++kk)
                    kf[ni][kk] = *(const bf16x8*)(&Kg[(ni * 16 + lr) * 72 + kk * 32 + lg * 8]);
        } else {
            const bf16_t* ktp = kp + (size_t)ttile * 64 * DH;
            #pragma unroll
            for (int ni = 0; ni < 4; ++ni)
                #pragma unroll
                for (int kk = 0; kk < 2; ++kk)
                    kf[ni][kk] = *(const bf16x8*)(ktp + (size_t)(ni * 16 + lr) * DH + kk * 32 + lg * 8);
        }

        // S = Q K^T  -> fp32 LDS (C layout: row = mi*16+lg*4+r, col = ni*16+lr)
        #pragma unroll
        for (int mi = 0; mi < 4; ++mi) {
            f32x4 S[4];
            #pragma unroll
            for (int ni = 0; ni < 4; ++ni) S[ni] = z4;
            #pragma unroll
            for (int kk = 0; kk < 2; ++kk)
                #pragma unroll
                for (int ni = 0; ni < 4; ++ni)
                    S[ni] = mfma16(Qf[mi][kk], kf[ni][kk], S[ni]);
            #pragma unroll
            for (int ni = 0; ni < 4; ++ni)
                #pragma unroll
                for (int r = 0; r < 4; ++r)
                    S_lds[(mi * 16 + lg * 4 + r) * 65 + ni * 16 + lr] = S[ni][r];
        }
        __syncthreads();

        // one-row-per-lane online softmax (row = lane)
        {
            const int row = lane;
            const bool gdrop = ((jt & 3) == 0);
            float tmax = -1e30f;
            for (int cc = 0; cc < 64; ++cc) {
                bool dp = isg ? (cc >= 16)
                              : ((ts == 1 && cc < row) || (ts == 9 && cc > row) || (gdrop && cc == 0));
                if (!dp) tmax = fmaxf(tmax, S_lds[row * 65 + cc]);
            }
            const float m2 = fmaxf(m_own, tmax);
            const float scr = expf(m_own - m2);
            float rs = 0.f;
            for (int cc = 0; cc < 64; ++cc) {
                bool dp = isg ? (cc >= 16)
                              : ((ts == 1 && cc < row) || (ts == 9 && cc > row) || (gdrop && cc == 0));
                float p = dp ? 0.f : expf(S_lds[row * 65 + cc] - m2);
                rs += p;
                P[row * 72 + cc] = (bf16_t)p;
            }
            m_own = m2;
            l_own = l_own * scr + rs;
            scr_lds[row] = scr;
        }
        __syncthreads();

        // rescale O (rows of C layout)
        #pragma unroll
        for (int mi = 0; mi < 4; ++mi)
            #pragma unroll
            for (int r = 0; r < 4; ++r) {
                float s = scr_lds[mi * 16 + lg * 4 + r];
                #pragma unroll
                for (int di = 0; di < 4; ++di) O[mi][di][r] *= s;
            }

        // PV: A = P (rows=q, k=key), B = V^T (k=key, col=d)
        #pragma unroll
        for (int kkp = 0; kkp < 2; ++kkp) {
            bf16x8 pa[4];
            #pragma unroll
            for (int mi = 0; mi < 4; ++mi)
                pa[mi] = *(const bf16x8*)(&P[(mi * 16 + lr) * 72 + kkp * 32 + lg * 8]);
            #pragma unroll
            for (int di = 0; di < 4; ++di) {
                bf16x8 vf;
                if (isg)
                    vf = *(const bf16x8*)(&VgT[(di * 16 + lr) * 72 + kkp * 32 + lg * 8]);
                else
                    vf = *(const bf16x8*)(vp + (size_t)(di * 16 + lr) * TT + ttile * 64 + kkp * 32 + lg * 8);
                #pragma unroll
                for (int mi = 0; mi < 4; ++mi) O[mi][di] = mfma16(pa[mi], vf, O[mi][di]);
            }
        }
        __syncthreads();   // PV reads done before next tile's S/P writes
    }

    linv_lds[lane] = 1.f / l_own;
    __syncthreads();

    // epilogue
    const size_t outbase = ((size_t)b * TT + c * WW + q4 * 64) * EE + h * DH;
    #pragma unroll
    for (int mi = 0; mi < 4; ++mi)
        #pragma unroll
        for (int r = 0; r < 4; ++r) {
            int row = mi * 16 + lg * 4 + r;
            float linv = linv_lds[row];
            #pragma unroll
            for (int di = 0; di < 4; ++di)
                out[outbase + (size_t)row * EE + di * 16 + lr] = O[mi][di][r] * linv;
        }
}

// ---------------- global-token attention: rows t=256g, full softmax over T -------------
__global__ __launch_bounds__(256) void k_gattn(const float* __restrict__ qg,
                                               const bf16_t* __restrict__ kgl,
                                               const bf16_t* __restrict__ vgl,
                                               float* __restrict__ out) {
    const int gx = blockIdx.x;
    const int g = gx & 15;
    const int bh = gx >> 4;
    const int b = bh / HH, h = bh % HH;
    const int tid = threadIdx.x;
    const int lane = tid & 63, w = tid >> 6;

    __shared__ float qrow[DH];
    __shared__ float sc[TT];
    __shared__ float red[256];

    if (tid < DH) qrow[tid] = qg[(((size_t)bh) * GG + g) * DH + tid];
    __syncthreads();

    const bf16_t* kp = kgl + (size_t)bh * TT * DH;
    float lmax = -1e30f;
    for (int t = tid; t < TT; t += 256) {
        const bf16_t* kr = kp + (size_t)t * DH;
        float s = 0.f;
        #pragma unroll
        for (int d0 = 0; d0 < DH; d0 += 8) {
            bf16x8 kv = *(const bf16x8*)(kr + d0);
            #pragma unroll
            for (int jj = 0; jj < 8; ++jj) s += qrow[d0 + jj] * (float)kv[jj];
        }
        sc[t] = s;
        lmax = fmaxf(lmax, s);
    }
    #pragma unroll
    for (int off = 32; off; off >>= 1) lmax = fmaxf(lmax, __shfl_xor(lmax, off));
    if (lane == 0) red[w] = lmax;
    __syncthreads();
    const float M = fmaxf(fmaxf(red[0], red[1]), fmaxf(red[2], red[3]));
    float lsum = 0.f;
    for (int t = tid; t < TT; t += 256) {
        float p = expf(sc[t] - M);
        sc[t] = p;
        lsum += p;
    }
    #pragma unroll
    for (int off = 32; off; off >>= 1) lsum += __shfl_xor(lsum, off);
    __syncthreads();                 // red[0..3] reads done
    if (lane == 0) red[64 + w] = lsum;
    __syncthreads();
    const float SUM = red[64] + red[65] + red[66] + red[67];
    __syncthreads();                 // everyone has SUM before red reuse

    const bf16_t* vp = vgl + (size_t)bh * TT * DH;
    float a0 = 0.f, a1 = 0.f, a2 = 0.f, a3 = 0.f;
    const int tbase = w * 1024;
    for (int t = tbase; t < tbase + 1024; t += 4) {
        a0 += sc[t] * (float)vp[(size_t)t * DH + lane];
        a1 += sc[t + 1] * (float)vp[(size_t)(t + 1) * DH + lane];
        a2 += sc[t + 2] * (float)vp[(size_t)(t + 2) * DH + lane];
        a3 += sc[t + 3] * (float)vp[(size_t)(t + 3) * DH + lane];
    }
    red[tid] = (a0 + a1) + (a2 + a3);
    __syncthreads();
    if (w == 0) {
        float tot = red[lane] + red[64 + lane] + red[128 + lane] + red[192 + lane];
        out[((size_t)b * TT + g * WW) * EE + h * DH + lane] = tot / SUM;
    }
}

// ---------------- launch ----------------
extern "C" void kernel_launch(void* const* d_in, const int* in_sizes, int n_in,
                              void* d_out, int out_size, void* d_ws, size_t ws_size,
                              hipStream_t stream) {
    const float* x   = (const float*)d_in[0];
    const float* Wq  = (const float*)d_in[1];
    const float* bq  = (const float*)d_in[2];
    const float* Wk  = (const float*)d_in[3];
    const float* bk  = (const float*)d_in[4];
    const float* Wv  = (const float*)d_in[5];
    const float* bv  = (const float*)d_in[6];
    const float* Wqg = (const float*)d_in[7];
    const float* bqg = (const float*)d_in[8];
    const float* Wkg = (const float*)d_in[9];
    const float* bkg = (const float*)d_in[10];
    const float* Wvg = (const float*)d_in[11];
    const float* bvg = (const float*)d_in[12];
    float* out = (float*)d_out;

    const size_t NX = (size_t)BB * TT * EE;          // 6,291,456
    const size_t NW = (size_t)EE * EE;               // 589,824
    const size_t NP = (size_t)BB * HH * TT * DH;     // 6,291,456

    bf16_t* xb   = (bf16_t*)d_ws;
    bf16_t* wt   = xb + NX;
    bf16_t* proj = wt + 5 * NW;
    bf16_t* vT   = proj + 5 * NP;
    float*  qg   = (float*)(vT + NP);

    (void)bvg; (void)in_sizes; (void)n_in; (void)out_size; (void)ws_size;

    k_prep_x<<<dim3((unsigned)(NX / (256 * 8))), 256, 0, stream>>>(x, xb);
    k_prep_w<<<dim3(12, 12, 5), 256, 0, stream>>>(Wq, Wk, Wv, Wkg, Wvg, wt);
    k_gemm<<<dim3(64, 6, 5), 256, 0, stream>>>(xb, wt, bq, bk, bv, bkg, bvg, proj);
    k_tv<<<dim3(64, 24), 256, 0, stream>>>(proj + 2 * NP, vT);
    k_qg<<<dim3(16, 2), 256, 0, stream>>>(x, Wqg, bqg, qg);
    k_lattn<<<dim3(1536), 64, 0, stream>>>(proj, proj + NP, vT, out);
    k_gattn<<<dim3(384), 256, 0, stream>>>(qg, proj + 3 * NP, proj + 4 * NP, out);
}

// Round 3
// 419.055 us; speedup vs baseline: 1.3034x; 1.3034x over previous
//
#include <hip/hip_runtime.h>
#include <stdint.h>
#include <stddef.h>

// Problem constants
#define BB 2
#define TT 4096
#define EE 768
#define HH 12
#define DH 64
#define WW 256
#define NCHUNK 16
#define GG 16

typedef __bf16 bf16_t;
typedef __bf16 bf16x8 __attribute__((ext_vector_type(8)));
typedef float f32x4 __attribute__((ext_vector_type(4)));

__device__ inline f32x4 mfma16(bf16x8 a, bf16x8 b, f32x4 c) {
    return __builtin_amdgcn_mfma_f32_16x16x32_bf16(a, b, c, 0, 0, 0);
}

// ---------------- prep: x (fp32) -> xb (bf16) ----------------
__global__ __launch_bounds__(256) void k_prep_x(const float* __restrict__ x,
                                                bf16_t* __restrict__ xb) {
    const int i = (blockIdx.x * 256 + threadIdx.x) * 8;
    f32x4 a = *(const f32x4*)(x + i);
    f32x4 b = *(const f32x4*)(x + i + 4);
    bf16x8 o;
    o[0] = (bf16_t)a[0]; o[1] = (bf16_t)a[1]; o[2] = (bf16_t)a[2]; o[3] = (bf16_t)a[3];
    o[4] = (bf16_t)b[0]; o[5] = (bf16_t)b[1]; o[6] = (bf16_t)b[2]; o[7] = (bf16_t)b[3];
    *(bf16x8*)(xb + i) = o;
}

// ---------------- prep: W (fp32, K x N) -> Wt (bf16, N x K), 5 weights ----------------
__global__ __launch_bounds__(256) void k_prep_w(const float* __restrict__ w0,
                                                const float* __restrict__ w1,
                                                const float* __restrict__ w2,
                                                const float* __restrict__ w3,
                                                const float* __restrict__ w4,
                                                bf16_t* __restrict__ wt) {
    const int z = blockIdx.z;
    const float* W = (z == 0) ? w0 : (z == 1) ? w1 : (z == 2) ? w2 : (z == 3) ? w3 : w4;
    const int k0 = blockIdx.x * 64;
    const int n0 = blockIdx.y * 64;
    const int tid = threadIdx.x;
    __shared__ __align__(16) bf16_t ls[64 * 65];
    #pragma unroll
    for (int i = 0; i < 16; ++i) {
        int idx = i * 256 + tid;
        int kr = idx >> 6, nc = idx & 63;
        ls[nc * 65 + kr] = (bf16_t)W[(size_t)(k0 + kr) * EE + n0 + nc];
    }
    __syncthreads();
    bf16_t* o = wt + (size_t)z * EE * EE;
    #pragma unroll
    for (int i = 0; i < 16; ++i) {
        int idx = i * 256 + tid;
        int nr = idx >> 6, kc = idx & 63;
        o[(size_t)(n0 + nr) * EE + k0 + kc] = ls[nr * 65 + kc];
    }
}

// ---------------- projection GEMM: proj[z] = xb @ W[z] + b[z]  (bf16 MFMA) --------------
// out layout: (B,H,T,Dh) bf16; z: 0=q(scaled 1/8) 1=k 2=v 3=kgl 4=vgl
__global__ __launch_bounds__(256) void k_gemm(const bf16_t* __restrict__ xb,
                                              const bf16_t* __restrict__ wt,
                                              const float* __restrict__ b0,
                                              const float* __restrict__ b1,
                                              const float* __restrict__ b2,
                                              const float* __restrict__ b3,
                                              const float* __restrict__ b4,
                                              bf16_t* __restrict__ proj) {
    const int tid = threadIdx.x;
    const int z = blockIdx.z;
    const int m0 = blockIdx.x * 128;
    const int n0 = blockIdx.y * 128;
    const float* bias = (z == 0) ? b0 : (z == 1) ? b1 : (z == 2) ? b2 : (z == 3) ? b3 : b4;
    const float scale = (z == 0) ? 0.125f : 1.0f;
    const bf16_t* wz = wt + (size_t)z * EE * EE;
    bf16_t* dst = proj + (size_t)z * BB * HH * TT * DH;

    __shared__ __align__(16) bf16_t lA[128 * 72];
    __shared__ __align__(16) bf16_t lB[128 * 72];

    const int lane = tid & 63, wid = tid >> 6;
    const int wr = wid >> 1, wc = wid & 1;
    const int lg = lane >> 4, lr = lane & 15;

    f32x4 acc[4][4];
    const f32x4 z4 = {0.f, 0.f, 0.f, 0.f};
    #pragma unroll
    for (int i = 0; i < 4; ++i)
        #pragma unroll
        for (int j = 0; j < 4; ++j) acc[i][j] = z4;

    for (int kt = 0; kt < 12; ++kt) {
        const int k0 = kt * 64;
        #pragma unroll
        for (int it = 0; it < 4; ++it) {
            int q = it * 256 + tid;       // 0..1023
            int row = q >> 3;             // 0..127
            int c8 = (q & 7) * 8;         // 0..56
            f32x4 av = *(const f32x4*)(xb + (size_t)(m0 + row) * EE + k0 + c8);
            *(f32x4*)(&lA[row * 72 + c8]) = av;
            f32x4 bv = *(const f32x4*)(wz + (size_t)(n0 + row) * EE + k0 + c8);
            *(f32x4*)(&lB[row * 72 + c8]) = bv;
        }
        __syncthreads();
        #pragma unroll
        for (int kk = 0; kk < 2; ++kk) {
            bf16x8 af[4], bfr[4];
            #pragma unroll
            for (int mi = 0; mi < 4; ++mi)
                af[mi] = *(const bf16x8*)(&lA[(wr * 64 + mi * 16 + lr) * 72 + kk * 32 + lg * 8]);
            #pragma unroll
            for (int ni = 0; ni < 4; ++ni)
                bfr[ni] = *(const bf16x8*)(&lB[(wc * 64 + ni * 16 + lr) * 72 + kk * 32 + lg * 8]);
            #pragma unroll
            for (int mi = 0; mi < 4; ++mi)
                #pragma unroll
                for (int ni = 0; ni < 4; ++ni)
                    acc[mi][ni] = mfma16(af[mi], bfr[ni], acc[mi][ni]);
        }
        __syncthreads();
    }

    #pragma unroll
    for (int mi = 0; mi < 4; ++mi)
        #pragma unroll
        for (int ni = 0; ni < 4; ++ni) {
            int n = n0 + wc * 64 + ni * 16 + lr;
            float bn = bias[n];
            int h = n >> 6, d = n & 63;
            #pragma unroll
            for (int r = 0; r < 4; ++r) {
                int m = m0 + wr * 64 + mi * 16 + lg * 4 + r;
                float v = (acc[mi][ni][r] + bn) * scale;
                int bb = m >> 12, t = m & 4095;
                dst[(((size_t)bb * HH + h) * TT + t) * DH + d] = (bf16_t)v;
            }
        }
}

// ---------------- transpose v: (B,H,T,Dh) -> (B,H,Dh,T) bf16 ----------------
__global__ __launch_bounds__(256) void k_tv(const bf16_t* __restrict__ v,
                                            bf16_t* __restrict__ vT) {
    __shared__ __align__(16) bf16_t ls[64 * 65];
    const int t0 = blockIdx.x * 64;
    const int bh = blockIdx.y;
    const int tid = threadIdx.x;
    const bf16_t* vp = v + ((size_t)bh * TT + t0) * DH;
    #pragma unroll
    for (int i = 0; i < 16; ++i) {
        int idx = i * 256 + tid;
        int tr = idx >> 6, dc = idx & 63;
        ls[dc * 65 + tr] = vp[(size_t)tr * DH + dc];
    }
    __syncthreads();
    bf16_t* op = vT + (size_t)bh * DH * TT + t0;
    #pragma unroll
    for (int i = 0; i < 16; ++i) {
        int idx = i * 256 + tid;
        int dr = idx >> 6, tc = idx & 63;
        op[(size_t)dr * TT + tc] = ls[dr * 65 + tc];
    }
}

// ---------------- qg projection: qg = (x[global] @ Wqg + bqg) * 1/8, fp32 ----------------
// out: (B,H,G,Dh) fp32
__global__ __launch_bounds__(256) void k_qg(const float* __restrict__ x,
                                            const float* __restrict__ Wqg,
                                            const float* __restrict__ bqg,
                                            float* __restrict__ qg) {
    const int g = blockIdx.x, b = blockIdx.y;
    const int tid = threadIdx.x;
    __shared__ float xr[EE];
    const float* xrow = x + ((size_t)b * TT + g * WW) * EE;
    for (int i = tid; i < EE; i += 256) xr[i] = xrow[i];
    __syncthreads();
    float a0 = bqg[tid], a1 = bqg[tid + 256], a2 = bqg[tid + 512];
    for (int e = 0; e < EE; ++e) {
        float xe = xr[e];
        const float* wrow = Wqg + (size_t)e * EE;
        a0 += xe * wrow[tid];
        a1 += xe * wrow[tid + 256];
        a2 += xe * wrow[tid + 512];
    }
    float accs[3] = {a0, a1, a2};
    #pragma unroll
    for (int j = 0; j < 3; ++j) {
        int n = tid + j * 256;
        int h = n >> 6, d = n & 63;
        qg[(((size_t)b * HH + h) * GG + g) * DH + d] = accs[j] * 0.125f;
    }
}

// ---------------- local (windowed + global-col) attention ----------------
// 1 wave per block; block handles 64 query rows of one (b,h,chunk,quarter).
// v3: wave-parallel shfl softmax on C-layout, __expf, slim LDS, no barriers in loop.
__global__ __launch_bounds__(64) void k_lattn(const bf16_t* __restrict__ qs,
                                              const bf16_t* __restrict__ ks,
                                              const bf16_t* __restrict__ vT,
                                              float* __restrict__ out) {
    const int gx = blockIdx.x;
    const int q4 = gx & 3;
    const int c = (gx >> 2) & 15;
    const int bh = gx >> 6;          // 0..23
    const int b = bh / HH, h = bh % HH;
    const int lane = threadIdx.x, lg = lane >> 4, lr = lane & 15;

    const bf16_t* qp = qs + ((size_t)bh * TT + c * WW + q4 * 64) * DH;
    const bf16_t* kp = ks + (size_t)bh * TT * DH;
    const bf16_t* vp = vT + (size_t)bh * DH * TT;

    __shared__ __align__(16) bf16_t P[64 * 72];     // 9216 B
    __shared__ __align__(16) bf16_t Kg[16 * 72];    // 2304 B  (global keys, [g][d])
    __shared__ __align__(16) bf16_t VgT[64 * 40];   // 5120 B  ([d][g], cols 16..31 = 0)

    // stage global K rows (16 x 64, vectorized)
    #pragma unroll
    for (int i = 0; i < 2; ++i) {
        int idx = i * 64 + lane;          // 0..127
        int r = idx >> 3, d8 = (idx & 7) * 8;
        *(bf16x8*)(&Kg[r * 72 + d8]) = *(const bf16x8*)(kp + (size_t)r * WW * DH + d8);
    }
    // stage global V^T (d-major, zero-padded cols 16..31)
    #pragma unroll
    for (int g = 0; g < 32; ++g)
        VgT[lane * 40 + g] = (g < 16) ? vp[(size_t)lane * TT + g * WW] : (bf16_t)0.f;

    // Q fragments (A operand): row = lr (+16*mi), k = lg*8 (+32*kk)
    bf16x8 Qf[4][2];
    #pragma unroll
    for (int mi = 0; mi < 4; ++mi)
        #pragma unroll
        for (int kk = 0; kk < 2; ++kk)
            Qf[mi][kk] = *(const bf16x8*)(qp + (size_t)(mi * 16 + lr) * DH + kk * 32 + lg * 8);

    f32x4 O[4][4];
    const f32x4 z4 = {0.f, 0.f, 0.f, 0.f};
    #pragma unroll
    for (int i = 0; i < 4; ++i)
        #pragma unroll
        for (int j = 0; j < 4; ++j) O[i][j] = z4;

    float m_own[16], l_own[16];
    #pragma unroll
    for (int i = 0; i < 16; ++i) { m_own[i] = -1e30f; l_own[i] = 0.f; }

    __syncthreads();   // staging visible (single wave; cheap)

    for (int ts = 0; ts < 10; ++ts) {
        const bool isg = (ts == 0);
        const int jt = q4 + ts - 1;
        const int ttile = 4 * (c - 1) + jt;   // global 64-key tile index
        if (!isg && (ttile < 0 || ttile > 63)) continue;
        const bool gdrop = !isg && ((jt & 3) == 0);

        // K fragments (B operand): col = key, k = d
        bf16x8 kf[4][2];
        if (isg) {
            #pragma unroll
            for (int kk = 0; kk < 2; ++kk)
                kf[0][kk] = *(const bf16x8*)(&Kg[lr * 72 + kk * 32 + lg * 8]);
        } else {
            const bf16_t* ktp = kp + (size_t)ttile * 64 * DH;
            #pragma unroll
            for (int ni = 0; ni < 4; ++ni)
                #pragma unroll
                for (int kk = 0; kk < 2; ++kk)
                    kf[ni][kk] = *(const bf16x8*)(ktp + (size_t)(ni * 16 + lr) * DH + kk * 32 + lg * 8);
        }

        #pragma unroll
        for (int mi = 0; mi < 4; ++mi) {
            f32x4 S[4] = {z4, z4, z4, z4};
            if (isg) {
                #pragma unroll
                for (int kk = 0; kk < 2; ++kk)
                    S[0] = mfma16(Qf[mi][kk], kf[0][kk], S[0]);
            } else {
                #pragma unroll
                for (int kk = 0; kk < 2; ++kk)
                    #pragma unroll
                    for (int ni = 0; ni < 4; ++ni)
                        S[ni] = mfma16(Qf[mi][kk], kf[ni][kk], S[ni]);
            }

            // wave-parallel online softmax on C layout: row = mi*16+lg*4+r, col = ni*16+lr
            #pragma unroll
            for (int r = 0; r < 4; ++r) {
                const int row = mi * 16 + lg * 4 + r;
                const int idx = mi * 4 + r;
                float sv[4];
                #pragma unroll
                for (int ni = 0; ni < 4; ++ni) {
                    const int cc = ni * 16 + lr;
                    bool ok = isg ? (ni == 0)
                                  : !((ts == 1 && cc < row) || (ts == 9 && cc > row) ||
                                      (gdrop && cc == 0));
                    sv[ni] = ok ? S[ni][r] : -1e30f;
                }
                float tmax = fmaxf(fmaxf(sv[0], sv[1]), fmaxf(sv[2], sv[3]));
                tmax = fmaxf(tmax, __shfl_xor(tmax, 1));
                tmax = fmaxf(tmax, __shfl_xor(tmax, 2));
                tmax = fmaxf(tmax, __shfl_xor(tmax, 4));
                tmax = fmaxf(tmax, __shfl_xor(tmax, 8));
                const float m2 = fmaxf(m_own[idx], tmax);
                const float scr = __expf(m_own[idx] - m2);
                float rs = 0.f;
                #pragma unroll
                for (int ni = 0; ni < 4; ++ni) {
                    float p = __expf(sv[ni] - m2);   // masked -> underflow to 0
                    rs += p;
                    P[row * 72 + ni * 16 + lr] = (bf16_t)p;
                }
                rs += __shfl_xor(rs, 1);
                rs += __shfl_xor(rs, 2);
                rs += __shfl_xor(rs, 4);
                rs += __shfl_xor(rs, 8);
                m_own[idx] = m2;
                l_own[idx] = l_own[idx] * scr + rs;
                #pragma unroll
                for (int di = 0; di < 4; ++di) O[mi][di][r] *= scr;
            }
        }

        // wait for all P ds_writes to land before cross-lane P reads (same wave,
        // no s_barrier needed); sched_barrier pins ordering (rule #18).
        asm volatile("s_waitcnt lgkmcnt(0)" ::: "memory");
        __builtin_amdgcn_sched_barrier(0);

        // PV: A = P (rows=q, k=key), B = V^T (k=key, col=d)
        #pragma unroll
        for (int kkp = 0; kkp < 2; ++kkp) {
            if (isg && kkp == 1) continue;   // global-tile keys 32..63 have P==0
            bf16x8 pa[4];
            #pragma unroll
            for (int mi = 0; mi < 4; ++mi)
                pa[mi] = *(const bf16x8*)(&P[(mi * 16 + lr) * 72 + kkp * 32 + lg * 8]);
            #pragma unroll
            for (int di = 0; di < 4; ++di) {
                bf16x8 vf;
                if (isg)
                    vf = *(const bf16x8*)(&VgT[(di * 16 + lr) * 40 + lg * 8]);
                else
                    vf = *(const bf16x8*)(vp + (size_t)(di * 16 + lr) * TT + ttile * 64 + kkp * 32 + lg * 8);
                #pragma unroll
                for (int mi = 0; mi < 4; ++mi) O[mi][di] = mfma16(pa[mi], vf, O[mi][di]);
            }
        }
    }

    // epilogue: lane owns l for exactly the rows it holds in C layout
    const size_t outbase = ((size_t)b * TT + c * WW + q4 * 64) * EE + h * DH;
    #pragma unroll
    for (int mi = 0; mi < 4; ++mi)
        #pragma unroll
        for (int r = 0; r < 4; ++r) {
            int row = mi * 16 + lg * 4 + r;
            float linv = 1.f / l_own[mi * 4 + r];
            #pragma unroll
            for (int di = 0; di < 4; ++di)
                out[outbase + (size_t)row * EE + di * 16 + lr] = O[mi][di][r] * linv;
        }
}

// ---------------- global-token attention: rows t=256g, full softmax over T -------------
__global__ __launch_bounds__(256) void k_gattn(const float* __restrict__ qg,
                                               const bf16_t* __restrict__ kgl,
                                               const bf16_t* __restrict__ vgl,
                                               float* __restrict__ out) {
    const int gx = blockIdx.x;
    const int g = gx & 15;
    const int bh = gx >> 4;
    const int b = bh / HH, h = bh % HH;
    const int tid = threadIdx.x;
    const int lane = tid & 63, w = tid >> 6;

    __shared__ float qrow[DH];
    __shared__ float sc[TT];
    __shared__ float red[256];

    if (tid < DH) qrow[tid] = qg[(((size_t)bh) * GG + g) * DH + tid];
    __syncthreads();

    const bf16_t* kp = kgl + (size_t)bh * TT * DH;
    float lmax = -1e30f;
    for (int t = tid; t < TT; t += 256) {
        const bf16_t* kr = kp + (size_t)t * DH;
        float s = 0.f;
        #pragma unroll
        for (int d0 = 0; d0 < DH; d0 += 8) {
            bf16x8 kv = *(const bf16x8*)(kr + d0);
            #pragma unroll
            for (int jj = 0; jj < 8; ++jj) s += qrow[d0 + jj] * (float)kv[jj];
        }
        sc[t] = s;
        lmax = fmaxf(lmax, s);
    }
    #pragma unroll
    for (int off = 32; off; off >>= 1) lmax = fmaxf(lmax, __shfl_xor(lmax, off));
    if (lane == 0) red[w] = lmax;
    __syncthreads();
    const float M = fmaxf(fmaxf(red[0], red[1]), fmaxf(red[2], red[3]));
    float lsum = 0.f;
    for (int t = tid; t < TT; t += 256) {
        float p = __expf(sc[t] - M);
        sc[t] = p;
        lsum += p;
    }
    #pragma unroll
    for (int off = 32; off; off >>= 1) lsum += __shfl_xor(lsum, off);
    __syncthreads();                 // red[0..3] reads done
    if (lane == 0) red[64 + w] = lsum;
    __syncthreads();
    const float SUM = red[64] + red[65] + red[66] + red[67];
    __syncthreads();                 // everyone has SUM before red reuse

    const bf16_t* vp = vgl + (size_t)bh * TT * DH;
    float a0 = 0.f, a1 = 0.f, a2 = 0.f, a3 = 0.f;
    const int tbase = w * 1024;
    for (int t = tbase; t < tbase + 1024; t += 4) {
        a0 += sc[t] * (float)vp[(size_t)t * DH + lane];
        a1 += sc[t + 1] * (float)vp[(size_t)(t + 1) * DH + lane];
        a2 += sc[t + 2] * (float)vp[(size_t)(t + 2) * DH + lane];
        a3 += sc[t + 3] * (float)vp[(size_t)(t + 3) * DH + lane];
    }
    red[tid] = (a0 + a1) + (a2 + a3);
    __syncthreads();
    if (w == 0) {
        float tot = red[lane] + red[64 + lane] + red[128 + lane] + red[192 + lane];
        out[((size_t)b * TT + g * WW) * EE + h * DH + lane] = tot / SUM;
    }
}

// ---------------- launch ----------------
extern "C" void kernel_launch(void* const* d_in, const int* in_sizes, int n_in,
                              void* d_out, int out_size, void* d_ws, size_t ws_size,
                              hipStream_t stream) {
    const float* x   = (const float*)d_in[0];
    const float* Wq  = (const float*)d_in[1];
    const float* bq  = (const float*)d_in[2];
    const float* Wk  = (const float*)d_in[3];
    const float* bk  = (const float*)d_in[4];
    const float* Wv  = (const float*)d_in[5];
    const float* bv  = (const float*)d_in[6];
    const float* Wqg = (const float*)d_in[7];
    const float* bqg = (const float*)d_in[8];
    const float* Wkg = (const float*)d_in[9];
    const float* bkg = (const float*)d_in[10];
    const float* Wvg = (const float*)d_in[11];
    const float* bvg = (const float*)d_in[12];
    float* out = (float*)d_out;

    const size_t NX = (size_t)BB * TT * EE;          // 6,291,456
    const size_t NW = (size_t)EE * EE;               // 589,824
    const size_t NP = (size_t)BB * HH * TT * DH;     // 6,291,456

    bf16_t* xb   = (bf16_t*)d_ws;
    bf16_t* wt   = xb + NX;
    bf16_t* proj = wt + 5 * NW;
    bf16_t* vT   = proj + 5 * NP;
    float*  qg   = (float*)(vT + NP);

    (void)bvg; (void)in_sizes; (void)n_in; (void)out_size; (void)ws_size;

    k_prep_x<<<dim3((unsigned)(NX / (256 * 8))), 256, 0, stream>>>(x, xb);
    k_prep_w<<<dim3(12, 12, 5), 256, 0, stream>>>(Wq, Wk, Wv, Wkg, Wvg, wt);
    k_gemm<<<dim3(64, 6, 5), 256, 0, stream>>>(xb, wt, bq, bk, bv, bkg, bvg, proj);
    k_tv<<<dim3(64, 24), 256, 0, stream>>>(proj + 2 * NP, vT);
    k_qg<<<dim3(16, 2), 256, 0, stream>>>(x, Wqg, bqg, qg);
    k_lattn<<<dim3(1536), 64, 0, stream>>>(proj, proj + NP, vT, out);
    k_gattn<<<dim3(384), 256, 0, stream>>>(qg, proj + 3 * NP, proj + 4 * NP, out);
}

// Round 4
// 371.641 us; speedup vs baseline: 1.4697x; 1.1276x over previous
//
#include <hip/hip_runtime.h>
#include <stdint.h>
#include <stddef.h>

// Problem constants
#define BB 2
#define TT 4096
#define EE 768
#define HH 12
#define DH 64
#define WW 256
#define NCHUNK 16
#define GG 16

typedef __bf16 bf16_t;
typedef __bf16 bf16x8 __attribute__((ext_vector_type(8)));
typedef float f32x4 __attribute__((ext_vector_type(4)));

__device__ inline f32x4 mfma16(bf16x8 a, bf16x8 b, f32x4 c) {
    return __builtin_amdgcn_mfma_f32_16x16x32_bf16(a, b, c, 0, 0, 0);
}

// ---------------- prep: x (fp32) -> xb (bf16) ----------------
__global__ __launch_bounds__(256) void k_prep_x(const float* __restrict__ x,
                                                bf16_t* __restrict__ xb) {
    const int i = (blockIdx.x * 256 + threadIdx.x) * 8;
    f32x4 a = *(const f32x4*)(x + i);
    f32x4 b = *(const f32x4*)(x + i + 4);
    bf16x8 o;
    o[0] = (bf16_t)a[0]; o[1] = (bf16_t)a[1]; o[2] = (bf16_t)a[2]; o[3] = (bf16_t)a[3];
    o[4] = (bf16_t)b[0]; o[5] = (bf16_t)b[1]; o[6] = (bf16_t)b[2]; o[7] = (bf16_t)b[3];
    *(bf16x8*)(xb + i) = o;
}

// ---------------- prep: W (fp32, K x N) -> Wt (bf16, N x K), 5 weights ----------------
__global__ __launch_bounds__(256) void k_prep_w(const float* __restrict__ w0,
                                                const float* __restrict__ w1,
                                                const float* __restrict__ w2,
                                                const float* __restrict__ w3,
                                                const float* __restrict__ w4,
                                                bf16_t* __restrict__ wt) {
    const int z = blockIdx.z;
    const float* W = (z == 0) ? w0 : (z == 1) ? w1 : (z == 2) ? w2 : (z == 3) ? w3 : w4;
    const int k0 = blockIdx.x * 64;
    const int n0 = blockIdx.y * 64;
    const int tid = threadIdx.x;
    __shared__ __align__(16) bf16_t ls[64 * 65];
    #pragma unroll
    for (int i = 0; i < 16; ++i) {
        int idx = i * 256 + tid;
        int kr = idx >> 6, nc = idx & 63;
        ls[nc * 65 + kr] = (bf16_t)W[(size_t)(k0 + kr) * EE + n0 + nc];
    }
    __syncthreads();
    bf16_t* o = wt + (size_t)z * EE * EE;
    #pragma unroll
    for (int i = 0; i < 16; ++i) {
        int idx = i * 256 + tid;
        int nr = idx >> 6, kc = idx & 63;
        o[(size_t)(n0 + nr) * EE + k0 + kc] = ls[nr * 65 + kc];
    }
}

// ---------------- projection GEMM: proj[z] = xb @ W[z] + b[z]  (bf16 MFMA) --------------
// out layout: (B,H,T,Dh) bf16; z: 0=q(scaled 1/8) 1=k 2=v 3=kgl 4=vgl
__global__ __launch_bounds__(256) void k_gemm(const bf16_t* __restrict__ xb,
                                              const bf16_t* __restrict__ wt,
                                              const float* __restrict__ b0,
                                              const float* __restrict__ b1,
                                              const float* __restrict__ b2,
                                              const float* __restrict__ b3,
                                              const float* __restrict__ b4,
                                              bf16_t* __restrict__ proj) {
    const int tid = threadIdx.x;
    const int z = blockIdx.z;
    const int m0 = blockIdx.x * 128;
    const int n0 = blockIdx.y * 128;
    const float* bias = (z == 0) ? b0 : (z == 1) ? b1 : (z == 2) ? b2 : (z == 3) ? b3 : b4;
    const float scale = (z == 0) ? 0.125f : 1.0f;
    const bf16_t* wz = wt + (size_t)z * EE * EE;
    bf16_t* dst = proj + (size_t)z * BB * HH * TT * DH;

    __shared__ __align__(16) bf16_t lA[128 * 72];
    __shared__ __align__(16) bf16_t lB[128 * 72];

    const int lane = tid & 63, wid = tid >> 6;
    const int wr = wid >> 1, wc = wid & 1;
    const int lg = lane >> 4, lr = lane & 15;

    f32x4 acc[4][4];
    const f32x4 z4 = {0.f, 0.f, 0.f, 0.f};
    #pragma unroll
    for (int i = 0; i < 4; ++i)
        #pragma unroll
        for (int j = 0; j < 4; ++j) acc[i][j] = z4;

    for (int kt = 0; kt < 12; ++kt) {
        const int k0 = kt * 64;
        #pragma unroll
        for (int it = 0; it < 4; ++it) {
            int q = it * 256 + tid;       // 0..1023
            int row = q >> 3;             // 0..127
            int c8 = (q & 7) * 8;         // 0..56
            f32x4 av = *(const f32x4*)(xb + (size_t)(m0 + row) * EE + k0 + c8);
            *(f32x4*)(&lA[row * 72 + c8]) = av;
            f32x4 bv = *(const f32x4*)(wz + (size_t)(n0 + row) * EE + k0 + c8);
            *(f32x4*)(&lB[row * 72 + c8]) = bv;
        }
        __syncthreads();
        #pragma unroll
        for (int kk = 0; kk < 2; ++kk) {
            bf16x8 af[4], bfr[4];
            #pragma unroll
            for (int mi = 0; mi < 4; ++mi)
                af[mi] = *(const bf16x8*)(&lA[(wr * 64 + mi * 16 + lr) * 72 + kk * 32 + lg * 8]);
            #pragma unroll
            for (int ni = 0; ni < 4; ++ni)
                bfr[ni] = *(const bf16x8*)(&lB[(wc * 64 + ni * 16 + lr) * 72 + kk * 32 + lg * 8]);
            #pragma unroll
            for (int mi = 0; mi < 4; ++mi)
                #pragma unroll
                for (int ni = 0; ni < 4; ++ni)
                    acc[mi][ni] = mfma16(af[mi], bfr[ni], acc[mi][ni]);
        }
        __syncthreads();
    }

    #pragma unroll
    for (int mi = 0; mi < 4; ++mi)
        #pragma unroll
        for (int ni = 0; ni < 4; ++ni) {
            int n = n0 + wc * 64 + ni * 16 + lr;
            float bn = bias[n];
            int h = n >> 6, d = n & 63;
            #pragma unroll
            for (int r = 0; r < 4; ++r) {
                int m = m0 + wr * 64 + mi * 16 + lg * 4 + r;
                float v = (acc[mi][ni][r] + bn) * scale;
                int bb = m >> 12, t = m & 4095;
                dst[(((size_t)bb * HH + h) * TT + t) * DH + d] = (bf16_t)v;
            }
        }
}

// ---------------- transpose v: (B,H,T,Dh) -> (B,H,Dh,T) bf16 ----------------
__global__ __launch_bounds__(256) void k_tv(const bf16_t* __restrict__ v,
                                            bf16_t* __restrict__ vT) {
    __shared__ __align__(16) bf16_t ls[64 * 65];
    const int t0 = blockIdx.x * 64;
    const int bh = blockIdx.y;
    const int tid = threadIdx.x;
    const bf16_t* vp = v + ((size_t)bh * TT + t0) * DH;
    #pragma unroll
    for (int i = 0; i < 16; ++i) {
        int idx = i * 256 + tid;
        int tr = idx >> 6, dc = idx & 63;
        ls[dc * 65 + tr] = vp[(size_t)tr * DH + dc];
    }
    __syncthreads();
    bf16_t* op = vT + (size_t)bh * DH * TT + t0;
    #pragma unroll
    for (int i = 0; i < 16; ++i) {
        int idx = i * 256 + tid;
        int dr = idx >> 6, tc = idx & 63;
        op[(size_t)dr * TT + tc] = ls[dr * 65 + tc];
    }
}

// ---------------- qg projection: qg = (x[global] @ Wqg + bqg) * 1/8, fp32 ----------------
// out: (B,H,G,Dh) fp32
__global__ __launch_bounds__(256) void k_qg(const float* __restrict__ x,
                                            const float* __restrict__ Wqg,
                                            const float* __restrict__ bqg,
                                            float* __restrict__ qg) {
    const int g = blockIdx.x, b = blockIdx.y;
    const int tid = threadIdx.x;
    __shared__ float xr[EE];
    const float* xrow = x + ((size_t)b * TT + g * WW) * EE;
    for (int i = tid; i < EE; i += 256) xr[i] = xrow[i];
    __syncthreads();
    float a0 = bqg[tid], a1 = bqg[tid + 256], a2 = bqg[tid + 512];
    for (int e = 0; e < EE; ++e) {
        float xe = xr[e];
        const float* wrow = Wqg + (size_t)e * EE;
        a0 += xe * wrow[tid];
        a1 += xe * wrow[tid + 256];
        a2 += xe * wrow[tid + 512];
    }
    float accs[3] = {a0, a1, a2};
    #pragma unroll
    for (int j = 0; j < 3; ++j) {
        int n = tid + j * 256;
        int h = n >> 6, d = n & 63;
        qg[(((size_t)b * HH + h) * GG + g) * DH + d] = accs[j] * 0.125f;
    }
}

// ---------------- local (windowed + global-col) attention ----------------
// v4: split-K across 2 waves per block (wave w takes tiles ts = w, w+2, ...),
// online-softmax partials merged via LDS. XCD-aware block swizzle clusters
// 3 (b,h) pairs per XCD for K/V L2 locality.
// LDS map (26880 B): [0,9216) P0 | [9216,18432) P1 | [18432,20736) Kg |
// [20736,25856) VgT | [25856,26880) ml.  Om (64x64 f32, 16384 B) overlays
// P0/P1 after both waves' tile loops complete.
__global__ __launch_bounds__(128, 3) void k_lattn(const bf16_t* __restrict__ qs,
                                                  const bf16_t* __restrict__ ks,
                                                  const bf16_t* __restrict__ vT,
                                                  float* __restrict__ out) {
    const int gx0 = blockIdx.x;
    const int gx = (gx0 & 7) * 192 + (gx0 >> 3);   // 3 consecutive bh per XCD
    const int q4 = gx & 3;
    const int c = (gx >> 2) & 15;
    const int bh = gx >> 6;          // 0..23
    const int b = bh / HH, h = bh % HH;
    const int tid = threadIdx.x;
    const int w = tid >> 6;          // wave id 0/1
    const int lane = tid & 63, lg = lane >> 4, lr = lane & 15;

    const bf16_t* qp = qs + ((size_t)bh * TT + c * WW + q4 * 64) * DH;
    const bf16_t* kp = ks + (size_t)bh * TT * DH;
    const bf16_t* vp = vT + (size_t)bh * DH * TT;

    __shared__ __align__(16) char smem[26880];
    bf16_t* Pw  = (bf16_t*)(smem + (size_t)w * 9216);
    bf16_t* Kg  = (bf16_t*)(smem + 18432);
    bf16_t* VgT = (bf16_t*)(smem + 20736);
    float*  Om  = (float*)smem;
    float*  ml  = (float*)(smem + 25856);   // [w][{m,l}][64]

    if (w == 0) {
        // stage global K rows (16 x 64, vectorized)
        #pragma unroll
        for (int i = 0; i < 2; ++i) {
            int idx = i * 64 + lane;          // 0..127
            int r = idx >> 3, d8 = (idx & 7) * 8;
            *(bf16x8*)(&Kg[r * 72 + d8]) = *(const bf16x8*)(kp + (size_t)r * WW * DH + d8);
        }
        // stage global V^T (d-major, zero-padded cols 16..31)
        #pragma unroll
        for (int g = 0; g < 32; ++g)
            VgT[lane * 40 + g] = (g < 16) ? vp[(size_t)lane * TT + g * WW] : (bf16_t)0.f;
    }

    // Q fragments (A operand): row = lr (+16*mi), k = lg*8 (+32*kk)
    bf16x8 Qf[4][2];
    #pragma unroll
    for (int mi = 0; mi < 4; ++mi)
        #pragma unroll
        for (int kk = 0; kk < 2; ++kk)
            Qf[mi][kk] = *(const bf16x8*)(qp + (size_t)(mi * 16 + lr) * DH + kk * 32 + lg * 8);

    f32x4 O[4][4];
    const f32x4 z4 = {0.f, 0.f, 0.f, 0.f};
    #pragma unroll
    for (int i = 0; i < 4; ++i)
        #pragma unroll
        for (int j = 0; j < 4; ++j) O[i][j] = z4;

    float m_own[16], l_own[16];
    #pragma unroll
    for (int i = 0; i < 16; ++i) { m_own[i] = -1e30f; l_own[i] = 0.f; }

    __syncthreads();   // staging visible to wave 0's MFMA reads

    for (int ts = w; ts < 10; ts += 2) {
        const bool isg = (ts == 0);
        const int jt = q4 + ts - 1;
        const int ttile = 4 * (c - 1) + jt;   // global 64-key tile index
        if (!isg && (ttile < 0 || ttile > 63)) continue;
        const bool gdrop = !isg && ((jt & 3) == 0);

        // K fragments (B operand): col = key, k = d
        bf16x8 kf[4][2];
        if (isg) {
            #pragma unroll
            for (int kk = 0; kk < 2; ++kk)
                kf[0][kk] = *(const bf16x8*)(&Kg[lr * 72 + kk * 32 + lg * 8]);
        } else {
            const bf16_t* ktp = kp + (size_t)ttile * 64 * DH;
            #pragma unroll
            for (int ni = 0; ni < 4; ++ni)
                #pragma unroll
                for (int kk = 0; kk < 2; ++kk)
                    kf[ni][kk] = *(const bf16x8*)(ktp + (size_t)(ni * 16 + lr) * DH + kk * 32 + lg * 8);
        }

        #pragma unroll
        for (int mi = 0; mi < 4; ++mi) {
            f32x4 S[4] = {z4, z4, z4, z4};
            if (isg) {
                #pragma unroll
                for (int kk = 0; kk < 2; ++kk)
                    S[0] = mfma16(Qf[mi][kk], kf[0][kk], S[0]);
            } else {
                #pragma unroll
                for (int kk = 0; kk < 2; ++kk)
                    #pragma unroll
                    for (int ni = 0; ni < 4; ++ni)
                        S[ni] = mfma16(Qf[mi][kk], kf[ni][kk], S[ni]);
            }

            // wave-parallel online softmax on C layout: row = mi*16+lg*4+r, col = ni*16+lr
            #pragma unroll
            for (int r = 0; r < 4; ++r) {
                const int row = mi * 16 + lg * 4 + r;
                const int idx = mi * 4 + r;
                float sv[4];
                #pragma unroll
                for (int ni = 0; ni < 4; ++ni) {
                    const int cc = ni * 16 + lr;
                    bool ok = isg ? (ni == 0)
                                  : !((ts == 1 && cc < row) || (ts == 9 && cc > row) ||
                                      (gdrop && cc == 0));
                    sv[ni] = ok ? S[ni][r] : -1e30f;
                }
                float tmax = fmaxf(fmaxf(sv[0], sv[1]), fmaxf(sv[2], sv[3]));
                tmax = fmaxf(tmax, __shfl_xor(tmax, 1));
                tmax = fmaxf(tmax, __shfl_xor(tmax, 2));
                tmax = fmaxf(tmax, __shfl_xor(tmax, 4));
                tmax = fmaxf(tmax, __shfl_xor(tmax, 8));
                const float m2 = fmaxf(m_own[idx], tmax);
                const float scr = __expf(m_own[idx] - m2);
                float rs = 0.f;
                #pragma unroll
                for (int ni = 0; ni < 4; ++ni) {
                    float p = __expf(sv[ni] - m2);   // masked -> underflow to 0
                    rs += p;
                    Pw[row * 72 + ni * 16 + lr] = (bf16_t)p;
                }
                rs += __shfl_xor(rs, 1);
                rs += __shfl_xor(rs, 2);
                rs += __shfl_xor(rs, 4);
                rs += __shfl_xor(rs, 8);
                m_own[idx] = m2;
                l_own[idx] = l_own[idx] * scr + rs;
                #pragma unroll
                for (int di = 0; di < 4; ++di) O[mi][di][r] *= scr;
            }
        }

        // wait for own-wave P ds_writes before cross-lane P reads; pin ordering.
        asm volatile("s_waitcnt lgkmcnt(0)" ::: "memory");
        __builtin_amdgcn_sched_barrier(0);

        // PV: A = P (rows=q, k=key), B = V^T (k=key, col=d)
        #pragma unroll
        for (int kkp = 0; kkp < 2; ++kkp) {
            if (isg && kkp == 1) continue;   // global-tile keys 32..63 have P==0
            bf16x8 pa[4];
            #pragma unroll
            for (int mi = 0; mi < 4; ++mi)
                pa[mi] = *(const bf16x8*)(&Pw[(mi * 16 + lr) * 72 + kkp * 32 + lg * 8]);
            #pragma unroll
            for (int di = 0; di < 4; ++di) {
                bf16x8 vf;
                if (isg)
                    vf = *(const bf16x8*)(&VgT[(di * 16 + lr) * 40 + lg * 8]);
                else
                    vf = *(const bf16x8*)(vp + (size_t)(di * 16 + lr) * TT + ttile * 64 + kkp * 32 + lg * 8);
                #pragma unroll
                for (int mi = 0; mi < 4; ++mi) O[mi][di] = mfma16(pa[mi], vf, O[mi][di]);
            }
        }
    }

    __syncthreads();   // both waves' tile loops done; P buffers dead -> Om overlay OK

    // publish per-wave m, l
    #pragma unroll
    for (int mi = 0; mi < 4; ++mi)
        #pragma unroll
        for (int r = 0; r < 4; ++r)
            if (lr == 0) {
                int row = mi * 16 + lg * 4 + r;
                ml[w * 128 + row]      = m_own[mi * 4 + r];
                ml[w * 128 + 64 + row] = l_own[mi * 4 + r];
            }
    __syncthreads();

    if (w == 1) {
        #pragma unroll
        for (int mi = 0; mi < 4; ++mi)
            #pragma unroll
            for (int r = 0; r < 4; ++r) {
                const int row = mi * 16 + lg * 4 + r;
                const int idx = mi * 4 + r;
                const float mstar = fmaxf(ml[row], m_own[idx]);
                const float s1 = __expf(m_own[idx] - mstar);
                #pragma unroll
                for (int di = 0; di < 4; ++di)
                    Om[row * 64 + di * 16 + lr] = O[mi][di][r] * s1;
                if (lr == 0) ml[128 + 64 + row] = l_own[idx] * s1;   // scaled l1
            }
    }
    __syncthreads();

    if (w == 0) {
        const size_t outbase = ((size_t)b * TT + c * WW + q4 * 64) * EE + h * DH;
        #pragma unroll
        for (int mi = 0; mi < 4; ++mi)
            #pragma unroll
            for (int r = 0; r < 4; ++r) {
                const int row = mi * 16 + lg * 4 + r;
                const int idx = mi * 4 + r;
                const float m1 = ml[128 + row];
                const float mstar = fmaxf(m_own[idx], m1);
                const float s0 = __expf(m_own[idx] - mstar);
                const float l = l_own[idx] * s0 + ml[128 + 64 + row];
                const float linv = 1.f / l;
                #pragma unroll
                for (int di = 0; di < 4; ++di)
                    out[outbase + (size_t)row * EE + di * 16 + lr] =
                        (O[mi][di][r] * s0 + Om[row * 64 + di * 16 + lr]) * linv;
            }
    }
}

// ---------------- global-token attention: rows t=256g, full softmax over T -------------
__global__ __launch_bounds__(256) void k_gattn(const float* __restrict__ qg,
                                               const bf16_t* __restrict__ kgl,
                                               const bf16_t* __restrict__ vgl,
                                               float* __restrict__ out) {
    const int gx = blockIdx.x;
    const int g = gx & 15;
    const int bh = gx >> 4;
    const int b = bh / HH, h = bh % HH;
    const int tid = threadIdx.x;
    const int lane = tid & 63, w = tid >> 6;

    __shared__ float qrow[DH];
    __shared__ float sc[TT];
    __shared__ float red[256];

    if (tid < DH) qrow[tid] = qg[(((size_t)bh) * GG + g) * DH + tid];
    __syncthreads();

    const bf16_t* kp = kgl + (size_t)bh * TT * DH;
    float lmax = -1e30f;
    for (int t = tid; t < TT; t += 256) {
        const bf16_t* kr = kp + (size_t)t * DH;
        float s = 0.f;
        #pragma unroll
        for (int d0 = 0; d0 < DH; d0 += 8) {
            bf16x8 kv = *(const bf16x8*)(kr + d0);
            #pragma unroll
            for (int jj = 0; jj < 8; ++jj) s += qrow[d0 + jj] * (float)kv[jj];
        }
        sc[t] = s;
        lmax = fmaxf(lmax, s);
    }
    #pragma unroll
    for (int off = 32; off; off >>= 1) lmax = fmaxf(lmax, __shfl_xor(lmax, off));
    if (lane == 0) red[w] = lmax;
    __syncthreads();
    const float M = fmaxf(fmaxf(red[0], red[1]), fmaxf(red[2], red[3]));
    float lsum = 0.f;
    for (int t = tid; t < TT; t += 256) {
        float p = __expf(sc[t] - M);
        sc[t] = p;
        lsum += p;
    }
    #pragma unroll
    for (int off = 32; off; off >>= 1) lsum += __shfl_xor(lsum, off);
    __syncthreads();                 // red[0..3] reads done
    if (lane == 0) red[64 + w] = lsum;
    __syncthreads();
    const float SUM = red[64] + red[65] + red[66] + red[67];
    __syncthreads();                 // everyone has SUM before red reuse

    const bf16_t* vp = vgl + (size_t)bh * TT * DH;
    float a0 = 0.f, a1 = 0.f, a2 = 0.f, a3 = 0.f;
    const int tbase = w * 1024;
    for (int t = tbase; t < tbase + 1024; t += 4) {
        a0 += sc[t] * (float)vp[(size_t)t * DH + lane];
        a1 += sc[t + 1] * (float)vp[(size_t)(t + 1) * DH + lane];
        a2 += sc[t + 2] * (float)vp[(size_t)(t + 2) * DH + lane];
        a3 += sc[t + 3] * (float)vp[(size_t)(t + 3) * DH + lane];
    }
    red[tid] = (a0 + a1) + (a2 + a3);
    __syncthreads();
    if (w == 0) {
        float tot = red[lane] + red[64 + lane] + red[128 + lane] + red[192 + lane];
        out[((size_t)b * TT + g * WW) * EE + h * DH + lane] = tot / SUM;
    }
}

// ---------------- launch ----------------
extern "C" void kernel_launch(void* const* d_in, const int* in_sizes, int n_in,
                              void* d_out, int out_size, void* d_ws, size_t ws_size,
                              hipStream_t stream) {
    const float* x   = (const float*)d_in[0];
    const float* Wq  = (const float*)d_in[1];
    const float* bq  = (const float*)d_in[2];
    const float* Wk  = (const float*)d_in[3];
    const float* bk  = (const float*)d_in[4];
    const float* Wv  = (const float*)d_in[5];
    const float* bv  = (const float*)d_in[6];
    const float* Wqg = (const float*)d_in[7];
    const float* bqg = (const float*)d_in[8];
    const float* Wkg = (const float*)d_in[9];
    const float* bkg = (const float*)d_in[10];
    const float* Wvg = (const float*)d_in[11];
    const float* bvg = (const float*)d_in[12];
    float* out = (float*)d_out;

    const size_t NX = (size_t)BB * TT * EE;          // 6,291,456
    const size_t NW = (size_t)EE * EE;               // 589,824
    const size_t NP = (size_t)BB * HH * TT * DH;     // 6,291,456

    bf16_t* xb   = (bf16_t*)d_ws;
    bf16_t* wt   = xb + NX;
    bf16_t* proj = wt + 5 * NW;
    bf16_t* vT   = proj + 5 * NP;
    float*  qg   = (float*)(vT + NP);

    (void)bvg; (void)in_sizes; (void)n_in; (void)out_size; (void)ws_size;

    k_prep_x<<<dim3((unsigned)(NX / (256 * 8))), 256, 0, stream>>>(x, xb);
    k_prep_w<<<dim3(12, 12, 5), 256, 0, stream>>>(Wq, Wk, Wv, Wkg, Wvg, wt);
    k_gemm<<<dim3(64, 6, 5), 256, 0, stream>>>(xb, wt, bq, bk, bv, bkg, bvg, proj);
    k_tv<<<dim3(64, 24), 256, 0, stream>>>(proj + 2 * NP, vT);
    k_qg<<<dim3(16, 2), 256, 0, stream>>>(x, Wqg, bqg, qg);
    k_lattn<<<dim3(1536), 128, 0, stream>>>(proj, proj + NP, vT, out);
    k_gattn<<<dim3(384), 256, 0, stream>>>(qg, proj + 3 * NP, proj + 4 * NP, out);
}

// Round 5
// 361.868 us; speedup vs baseline: 1.5094x; 1.0270x over previous
//
#include <hip/hip_runtime.h>
#include <stdint.h>
#include <stddef.h>

// Problem constants
#define BB 2
#define TT 4096
#define EE 768
#define HH 12
#define DH 64
#define WW 256
#define NCHUNK 16
#define GG 16

typedef __bf16 bf16_t;
typedef __bf16 bf16x8 __attribute__((ext_vector_type(8)));
typedef float f32x4 __attribute__((ext_vector_type(4)));

__device__ inline f32x4 mfma16(bf16x8 a, bf16x8 b, f32x4 c) {
    return __builtin_amdgcn_mfma_f32_16x16x32_bf16(a, b, c, 0, 0, 0);
}

__device__ inline void gload16(const void* g, void* l) {
    __builtin_amdgcn_global_load_lds(
        (const __attribute__((address_space(1))) void*)g,
        (__attribute__((address_space(3))) void*)l, 16, 0, 0);
}

// ---------------- prep: x (fp32) -> xb (bf16) ----------------
__global__ __launch_bounds__(256) void k_prep_x(const float* __restrict__ x,
                                                bf16_t* __restrict__ xb) {
    const int i = (blockIdx.x * 256 + threadIdx.x) * 8;
    f32x4 a = *(const f32x4*)(x + i);
    f32x4 b = *(const f32x4*)(x + i + 4);
    bf16x8 o;
    o[0] = (bf16_t)a[0]; o[1] = (bf16_t)a[1]; o[2] = (bf16_t)a[2]; o[3] = (bf16_t)a[3];
    o[4] = (bf16_t)b[0]; o[5] = (bf16_t)b[1]; o[6] = (bf16_t)b[2]; o[7] = (bf16_t)b[3];
    *(bf16x8*)(xb + i) = o;
}

// ---------------- prep: W (fp32, K x N) -> Wt (bf16, N x K), 5 weights ----------------
__global__ __launch_bounds__(256) void k_prep_w(const float* __restrict__ w0,
                                                const float* __restrict__ w1,
                                                const float* __restrict__ w2,
                                                const float* __restrict__ w3,
                                                const float* __restrict__ w4,
                                                bf16_t* __restrict__ wt) {
    const int z = blockIdx.z;
    const float* W = (z == 0) ? w0 : (z == 1) ? w1 : (z == 2) ? w2 : (z == 3) ? w3 : w4;
    const int k0 = blockIdx.x * 64;
    const int n0 = blockIdx.y * 64;
    const int tid = threadIdx.x;
    __shared__ __align__(16) bf16_t ls[64 * 65];
    #pragma unroll
    for (int i = 0; i < 16; ++i) {
        int idx = i * 256 + tid;
        int kr = idx >> 6, nc = idx & 63;
        ls[nc * 65 + kr] = (bf16_t)W[(size_t)(k0 + kr) * EE + n0 + nc];
    }
    __syncthreads();
    bf16_t* o = wt + (size_t)z * EE * EE;
    #pragma unroll
    for (int i = 0; i < 16; ++i) {
        int idx = i * 256 + tid;
        int nr = idx >> 6, kc = idx & 63;
        o[(size_t)(n0 + nr) * EE + k0 + kc] = ls[nr * 65 + kc];
    }
}

// ---------------- projection GEMM: proj[z] = xb @ W[z] + b[z]  (bf16 MFMA) --------------
// m97-style: linear LDS + global_load_lds width-16 staging.
// out layout: (B,H,T,Dh) bf16; z: 0=q(scaled 1/8) 1=k 2=v 3=kgl 4=vgl
__global__ __launch_bounds__(256) void k_gemm(const bf16_t* __restrict__ xb,
                                              const bf16_t* __restrict__ wt,
                                              const float* __restrict__ b0,
                                              const float* __restrict__ b1,
                                              const float* __restrict__ b2,
                                              const float* __restrict__ b3,
                                              const float* __restrict__ b4,
                                              bf16_t* __restrict__ proj) {
    const int tid = threadIdx.x;
    const int z = blockIdx.z;
    const int m0 = blockIdx.x * 128;
    const int n0 = blockIdx.y * 128;
    const float* bias = (z == 0) ? b0 : (z == 1) ? b1 : (z == 2) ? b2 : (z == 3) ? b3 : b4;
    const float scale = (z == 0) ? 0.125f : 1.0f;
    const bf16_t* wz = wt + (size_t)z * EE * EE;
    bf16_t* dst = proj + (size_t)z * BB * HH * TT * DH;

    __shared__ __align__(16) bf16_t lA[128 * 64];
    __shared__ __align__(16) bf16_t lB[128 * 64];

    const int lane = tid & 63, wid = tid >> 6;
    const int wr = wid >> 1, wc = wid & 1;
    const int lg = lane >> 4, lr = lane & 15;
    const int srow = lane >> 3;        // staging row within 8-row segment
    const int scol = (lane & 7) * 8;   // staging col (elements)

    f32x4 acc[4][4];
    const f32x4 z4 = {0.f, 0.f, 0.f, 0.f};
    #pragma unroll
    for (int i = 0; i < 4; ++i)
        #pragma unroll
        for (int j = 0; j < 4; ++j) acc[i][j] = z4;

    for (int kt = 0; kt < 12; ++kt) {
        const int k0 = kt * 64;
        #pragma unroll
        for (int i = 0; i < 4; ++i) {
            const int seg = wid * 4 + i;             // 0..15, uniform per wave
            const int row = seg * 8 + srow;          // 0..127
            gload16(xb + (size_t)(m0 + row) * EE + k0 + scol, &lA[seg * 512]);
            gload16(wz + (size_t)(n0 + row) * EE + k0 + scol, &lB[seg * 512]);
        }
        __syncthreads();   // drains vmcnt -> LDS staging visible
        #pragma unroll
        for (int kk = 0; kk < 2; ++kk) {
            bf16x8 af[4], bfr[4];
            #pragma unroll
            for (int mi = 0; mi < 4; ++mi)
                af[mi] = *(const bf16x8*)(&lA[(wr * 64 + mi * 16 + lr) * 64 + kk * 32 + lg * 8]);
            #pragma unroll
            for (int ni = 0; ni < 4; ++ni)
                bfr[ni] = *(const bf16x8*)(&lB[(wc * 64 + ni * 16 + lr) * 64 + kk * 32 + lg * 8]);
            #pragma unroll
            for (int mi = 0; mi < 4; ++mi)
                #pragma unroll
                for (int ni = 0; ni < 4; ++ni)
                    acc[mi][ni] = mfma16(af[mi], bfr[ni], acc[mi][ni]);
        }
        __syncthreads();
    }

    #pragma unroll
    for (int mi = 0; mi < 4; ++mi)
        #pragma unroll
        for (int ni = 0; ni < 4; ++ni) {
            int n = n0 + wc * 64 + ni * 16 + lr;
            float bn = bias[n];
            int h = n >> 6, d = n & 63;
            #pragma unroll
            for (int r = 0; r < 4; ++r) {
                int m = m0 + wr * 64 + mi * 16 + lg * 4 + r;
                float v = (acc[mi][ni][r] + bn) * scale;
                int bb = m >> 12, t = m & 4095;
                dst[(((size_t)bb * HH + h) * TT + t) * DH + d] = (bf16_t)v;
            }
        }
}

// ---------------- transpose v: (B,H,T,Dh) -> (B,H,Dh,T) bf16 ----------------
__global__ __launch_bounds__(256) void k_tv(const bf16_t* __restrict__ v,
                                            bf16_t* __restrict__ vT) {
    __shared__ __align__(16) bf16_t ls[64 * 65];
    const int t0 = blockIdx.x * 64;
    const int bh = blockIdx.y;
    const int tid = threadIdx.x;
    const bf16_t* vp = v + ((size_t)bh * TT + t0) * DH;
    #pragma unroll
    for (int i = 0; i < 16; ++i) {
        int idx = i * 256 + tid;
        int tr = idx >> 6, dc = idx & 63;
        ls[dc * 65 + tr] = vp[(size_t)tr * DH + dc];
    }
    __syncthreads();
    bf16_t* op = vT + (size_t)bh * DH * TT + t0;
    #pragma unroll
    for (int i = 0; i < 16; ++i) {
        int idx = i * 256 + tid;
        int dr = idx >> 6, tc = idx & 63;
        op[(size_t)dr * TT + tc] = ls[dr * 65 + tc];
    }
}

// ---------------- qg projection: qg = (x[global] @ Wqg + bqg) * 1/8, fp32 ----------------
// out: (B,H,G,Dh) fp32
__global__ __launch_bounds__(256) void k_qg(const float* __restrict__ x,
                                            const float* __restrict__ Wqg,
                                            const float* __restrict__ bqg,
                                            float* __restrict__ qg) {
    const int g = blockIdx.x, b = blockIdx.y;
    const int tid = threadIdx.x;
    __shared__ float xr[EE];
    const float* xrow = x + ((size_t)b * TT + g * WW) * EE;
    for (int i = tid; i < EE; i += 256) xr[i] = xrow[i];
    __syncthreads();
    float a0 = bqg[tid], a1 = bqg[tid + 256], a2 = bqg[tid + 512];
    for (int e = 0; e < EE; ++e) {
        float xe = xr[e];
        const float* wrow = Wqg + (size_t)e * EE;
        a0 += xe * wrow[tid];
        a1 += xe * wrow[tid + 256];
        a2 += xe * wrow[tid + 512];
    }
    float accs[3] = {a0, a1, a2};
    #pragma unroll
    for (int j = 0; j < 3; ++j) {
        int n = tid + j * 256;
        int h = n >> 6, d = n & 63;
        qg[(((size_t)b * HH + h) * GG + g) * DH + d] = accs[j] * 0.125f;
    }
}

// ---------------- local (windowed + global-col) attention ----------------
// v5: split-K across 2 waves (as v4) but WITHOUT the VGPR clamp that caused
// spilling (launch_bounds min-waves removed; allocator takes ~170 VGPR ->
// 3 waves/SIMD naturally, zero scratch).
__global__ __launch_bounds__(128) void k_lattn(const bf16_t* __restrict__ qs,
                                               const bf16_t* __restrict__ ks,
                                               const bf16_t* __restrict__ vT,
                                               float* __restrict__ out) {
    const int gx0 = blockIdx.x;
    const int gx = (gx0 & 7) * 192 + (gx0 >> 3);   // 3 consecutive bh per XCD
    const int q4 = gx & 3;
    const int c = (gx >> 2) & 15;
    const int bh = gx >> 6;          // 0..23
    const int b = bh / HH, h = bh % HH;
    const int tid = threadIdx.x;
    const int w = tid >> 6;          // wave id 0/1
    const int lane = tid & 63, lg = lane >> 4, lr = lane & 15;

    const bf16_t* qp = qs + ((size_t)bh * TT + c * WW + q4 * 64) * DH;
    const bf16_t* kp = ks + (size_t)bh * TT * DH;
    const bf16_t* vp = vT + (size_t)bh * DH * TT;

    __shared__ __align__(16) char smem[26880];
    bf16_t* Pw  = (bf16_t*)(smem + (size_t)w * 9216);
    bf16_t* Kg  = (bf16_t*)(smem + 18432);
    bf16_t* VgT = (bf16_t*)(smem + 20736);
    float*  Om  = (float*)smem;
    float*  ml  = (float*)(smem + 25856);   // [w][{m,l}][64]

    if (w == 0) {
        // stage global K rows (16 x 64, vectorized)
        #pragma unroll
        for (int i = 0; i < 2; ++i) {
            int idx = i * 64 + lane;          // 0..127
            int r = idx >> 3, d8 = (idx & 7) * 8;
            *(bf16x8*)(&Kg[r * 72 + d8]) = *(const bf16x8*)(kp + (size_t)r * WW * DH + d8);
        }
        // stage global V^T (d-major, zero-padded cols 16..31)
        #pragma unroll
        for (int g = 0; g < 32; ++g)
            VgT[lane * 40 + g] = (g < 16) ? vp[(size_t)lane * TT + g * WW] : (bf16_t)0.f;
    }

    // Q fragments (A operand): row = lr (+16*mi), k = lg*8 (+32*kk)
    bf16x8 Qf[4][2];
    #pragma unroll
    for (int mi = 0; mi < 4; ++mi)
        #pragma unroll
        for (int kk = 0; kk < 2; ++kk)
            Qf[mi][kk] = *(const bf16x8*)(qp + (size_t)(mi * 16 + lr) * DH + kk * 32 + lg * 8);

    f32x4 O[4][4];
    const f32x4 z4 = {0.f, 0.f, 0.f, 0.f};
    #pragma unroll
    for (int i = 0; i < 4; ++i)
        #pragma unroll
        for (int j = 0; j < 4; ++j) O[i][j] = z4;

    float m_own[16], l_own[16];
    #pragma unroll
    for (int i = 0; i < 16; ++i) { m_own[i] = -1e30f; l_own[i] = 0.f; }

    __syncthreads();   // staging visible to wave 0's MFMA reads

    for (int ts = w; ts < 10; ts += 2) {
        const bool isg = (ts == 0);
        const int jt = q4 + ts - 1;
        const int ttile = 4 * (c - 1) + jt;   // global 64-key tile index
        if (!isg && (ttile < 0 || ttile > 63)) continue;
        const bool gdrop = !isg && ((jt & 3) == 0);

        // K fragments (B operand): col = key, k = d
        bf16x8 kf[4][2];
        if (isg) {
            #pragma unroll
            for (int kk = 0; kk < 2; ++kk)
                kf[0][kk] = *(const bf16x8*)(&Kg[lr * 72 + kk * 32 + lg * 8]);
        } else {
            const bf16_t* ktp = kp + (size_t)ttile * 64 * DH;
            #pragma unroll
            for (int ni = 0; ni < 4; ++ni)
                #pragma unroll
                for (int kk = 0; kk < 2; ++kk)
                    kf[ni][kk] = *(const bf16x8*)(ktp + (size_t)(ni * 16 + lr) * DH + kk * 32 + lg * 8);
        }

        #pragma unroll
        for (int mi = 0; mi < 4; ++mi) {
            f32x4 S[4] = {z4, z4, z4, z4};
            if (isg) {
                #pragma unroll
                for (int kk = 0; kk < 2; ++kk)
                    S[0] = mfma16(Qf[mi][kk], kf[0][kk], S[0]);
            } else {
                #pragma unroll
                for (int kk = 0; kk < 2; ++kk)
                    #pragma unroll
                    for (int ni = 0; ni < 4; ++ni)
                        S[ni] = mfma16(Qf[mi][kk], kf[ni][kk], S[ni]);
            }

            // wave-parallel online softmax on C layout: row = mi*16+lg*4+r, col = ni*16+lr
            #pragma unroll
            for (int r = 0; r < 4; ++r) {
                const int row = mi * 16 + lg * 4 + r;
                const int idx = mi * 4 + r;
                float sv[4];
                #pragma unroll
                for (int ni = 0; ni < 4; ++ni) {
                    const int cc = ni * 16 + lr;
                    bool ok = isg ? (ni == 0)
                                  : !((ts == 1 && cc < row) || (ts == 9 && cc > row) ||
                                      (gdrop && cc == 0));
                    sv[ni] = ok ? S[ni][r] : -1e30f;
                }
                float tmax = fmaxf(fmaxf(sv[0], sv[1]), fmaxf(sv[2], sv[3]));
                tmax = fmaxf(tmax, __shfl_xor(tmax, 1));
                tmax = fmaxf(tmax, __shfl_xor(tmax, 2));
                tmax = fmaxf(tmax, __shfl_xor(tmax, 4));
                tmax = fmaxf(tmax, __shfl_xor(tmax, 8));
                const float m2 = fmaxf(m_own[idx], tmax);
                const float scr = __expf(m_own[idx] - m2);
                float rs = 0.f;
                #pragma unroll
                for (int ni = 0; ni < 4; ++ni) {
                    float p = __expf(sv[ni] - m2);   // masked -> underflow to 0
                    rs += p;
                    Pw[row * 72 + ni * 16 + lr] = (bf16_t)p;
                }
                rs += __shfl_xor(rs, 1);
                rs += __shfl_xor(rs, 2);
                rs += __shfl_xor(rs, 4);
                rs += __shfl_xor(rs, 8);
                m_own[idx] = m2;
                l_own[idx] = l_own[idx] * scr + rs;
                #pragma unroll
                for (int di = 0; di < 4; ++di) O[mi][di][r] *= scr;
            }
        }

        // wait for own-wave P ds_writes before cross-lane P reads; pin ordering.
        asm volatile("s_waitcnt lgkmcnt(0)" ::: "memory");
        __builtin_amdgcn_sched_barrier(0);

        // PV: A = P (rows=q, k=key), B = V^T (k=key, col=d)
        #pragma unroll
        for (int kkp = 0; kkp < 2; ++kkp) {
            if (isg && kkp == 1) continue;   // global-tile keys 32..63 have P==0
            bf16x8 pa[4];
            #pragma unroll
            for (int mi = 0; mi < 4; ++mi)
                pa[mi] = *(const bf16x8*)(&Pw[(mi * 16 + lr) * 72 + kkp * 32 + lg * 8]);
            #pragma unroll
            for (int di = 0; di < 4; ++di) {
                bf16x8 vf;
                if (isg)
                    vf = *(const bf16x8*)(&VgT[(di * 16 + lr) * 40 + lg * 8]);
                else
                    vf = *(const bf16x8*)(vp + (size_t)(di * 16 + lr) * TT + ttile * 64 + kkp * 32 + lg * 8);
                #pragma unroll
                for (int mi = 0; mi < 4; ++mi) O[mi][di] = mfma16(pa[mi], vf, O[mi][di]);
            }
        }
    }

    __syncthreads();   // both waves' tile loops done; P buffers dead -> Om overlay OK

    // publish per-wave m, l
    #pragma unroll
    for (int mi = 0; mi < 4; ++mi)
        #pragma unroll
        for (int r = 0; r < 4; ++r)
            if (lr == 0) {
                int row = mi * 16 + lg * 4 + r;
                ml[w * 128 + row]      = m_own[mi * 4 + r];
                ml[w * 128 + 64 + row] = l_own[mi * 4 + r];
            }
    __syncthreads();

    if (w == 1) {
        #pragma unroll
        for (int mi = 0; mi < 4; ++mi)
            #pragma unroll
            for (int r = 0; r < 4; ++r) {
                const int row = mi * 16 + lg * 4 + r;
                const int idx = mi * 4 + r;
                const float mstar = fmaxf(ml[row], m_own[idx]);
                const float s1 = __expf(m_own[idx] - mstar);
                #pragma unroll
                for (int di = 0; di < 4; ++di)
                    Om[row * 64 + di * 16 + lr] = O[mi][di][r] * s1;
                if (lr == 0) ml[128 + 64 + row] = l_own[idx] * s1;   // scaled l1
            }
    }
    __syncthreads();

    if (w == 0) {
        const size_t outbase = ((size_t)b * TT + c * WW + q4 * 64) * EE + h * DH;
        #pragma unroll
        for (int mi = 0; mi < 4; ++mi)
            #pragma unroll
            for (int r = 0; r < 4; ++r) {
                const int row = mi * 16 + lg * 4 + r;
                const int idx = mi * 4 + r;
                const float m1 = ml[128 + row];
                const float mstar = fmaxf(m_own[idx], m1);
                const float s0 = __expf(m_own[idx] - mstar);
                const float l = l_own[idx] * s0 + ml[128 + 64 + row];
                const float linv = 1.f / l;
                #pragma unroll
                for (int di = 0; di < 4; ++di)
                    out[outbase + (size_t)row * EE + di * 16 + lr] =
                        (O[mi][di][r] * s0 + Om[row * 64 + di * 16 + lr]) * linv;
            }
    }
}

// ---------------- global-token attention: rows t=256g, full softmax over T -------------
__global__ __launch_bounds__(256) void k_gattn(const float* __restrict__ qg,
                                               const bf16_t* __restrict__ kgl,
                                               const bf16_t* __restrict__ vgl,
                                               float* __restrict__ out) {
    const int gx = blockIdx.x;
    const int g = gx & 15;
    const int bh = gx >> 4;
    const int b = bh / HH, h = bh % HH;
    const int tid = threadIdx.x;
    const int lane = tid & 63, w = tid >> 6;

    __shared__ float qrow[DH];
    __shared__ float sc[TT];
    __shared__ float red[256];

    if (tid < DH) qrow[tid] = qg[(((size_t)bh) * GG + g) * DH + tid];
    __syncthreads();

    const bf16_t* kp = kgl + (size_t)bh * TT * DH;
    float lmax = -1e30f;
    for (int t = tid; t < TT; t += 256) {
        const bf16_t* kr = kp + (size_t)t * DH;
        float s = 0.f;
        #pragma unroll
        for (int d0 = 0; d0 < DH; d0 += 8) {
            bf16x8 kv = *(const bf16x8*)(kr + d0);
            #pragma unroll
            for (int jj = 0; jj < 8; ++jj) s += qrow[d0 + jj] * (float)kv[jj];
        }
        sc[t] = s;
        lmax = fmaxf(lmax, s);
    }
    #pragma unroll
    for (int off = 32; off; off >>= 1) lmax = fmaxf(lmax, __shfl_xor(lmax, off));
    if (lane == 0) red[w] = lmax;
    __syncthreads();
    const float M = fmaxf(fmaxf(red[0], red[1]), fmaxf(red[2], red[3]));
    float lsum = 0.f;
    for (int t = tid; t < TT; t += 256) {
        float p = __expf(sc[t] - M);
        sc[t] = p;
        lsum += p;
    }
    #pragma unroll
    for (int off = 32; off; off >>= 1) lsum += __shfl_xor(lsum, off);
    __syncthreads();                 // red[0..3] reads done
    if (lane == 0) red[64 + w] = lsum;
    __syncthreads();
    const float SUM = red[64] + red[65] + red[66] + red[67];
    __syncthreads();                 // everyone has SUM before red reuse

    const bf16_t* vp = vgl + (size_t)bh * TT * DH;
    float a0 = 0.f, a1 = 0.f, a2 = 0.f, a3 = 0.f;
    const int tbase = w * 1024;
    for (int t = tbase; t < tbase + 1024; t += 4) {
        a0 += sc[t] * (float)vp[(size_t)t * DH + lane];
        a1 += sc[t + 1] * (float)vp[(size_t)(t + 1) * DH + lane];
        a2 += sc[t + 2] * (float)vp[(size_t)(t + 2) * DH + lane];
        a3 += sc[t + 3] * (float)vp[(size_t)(t + 3) * DH + lane];
    }
    red[tid] = (a0 + a1) + (a2 + a3);
    __syncthreads();
    if (w == 0) {
        float tot = red[lane] + red[64 + lane] + red[128 + lane] + red[192 + lane];
        out[((size_t)b * TT + g * WW) * EE + h * DH + lane] = tot / SUM;
    }
}

// ---------------- launch ----------------
extern "C" void kernel_launch(void* const* d_in, const int* in_sizes, int n_in,
                              void* d_out, int out_size, void* d_ws, size_t ws_size,
                              hipStream_t stream) {
    const float* x   = (const float*)d_in[0];
    const float* Wq  = (const float*)d_in[1];
    const float* bq  = (const float*)d_in[2];
    const float* Wk  = (const float*)d_in[3];
    const float* bk  = (const float*)d_in[4];
    const float* Wv  = (const float*)d_in[5];
    const float* bv  = (const float*)d_in[6];
    const float* Wqg = (const float*)d_in[7];
    const float* bqg = (const float*)d_in[8];
    const float* Wkg = (const float*)d_in[9];
    const float* bkg = (const float*)d_in[10];
    const float* Wvg = (const float*)d_in[11];
    const float* bvg = (const float*)d_in[12];
    float* out = (float*)d_out;

    const size_t NX = (size_t)BB * TT * EE;          // 6,291,456
    const size_t NW = (size_t)EE * EE;               // 589,824
    const size_t NP = (size_t)BB * HH * TT * DH;     // 6,291,456

    bf16_t* xb   = (bf16_t*)d_ws;
    bf16_t* wt   = xb + NX;
    bf16_t* proj = wt + 5 * NW;
    bf16_t* vT   = proj + 5 * NP;
    float*  qg   = (float*)(vT + NP);

    (void)bvg; (void)in_sizes; (void)n_in; (void)out_size; (void)ws_size;

    k_prep_x<<<dim3((unsigned)(NX / (256 * 8))), 256, 0, stream>>>(x, xb);
    k_prep_w<<<dim3(12, 12, 5), 256, 0, stream>>>(Wq, Wk, Wv, Wkg, Wvg, wt);
    k_gemm<<<dim3(64, 6, 5), 256, 0, stream>>>(xb, wt, bq, bk, bv, bkg, bvg, proj);
    k_tv<<<dim3(64, 24), 256, 0, stream>>>(proj + 2 * NP, vT);
    k_qg<<<dim3(16, 2), 256, 0, stream>>>(x, Wqg, bqg, qg);
    k_lattn<<<dim3(1536), 128, 0, stream>>>(proj, proj + NP, vT, out);
    k_gattn<<<dim3(384), 256, 0, stream>>>(qg, proj + 3 * NP, proj + 4 * NP, out);
}

// Round 6
// 353.662 us; speedup vs baseline: 1.5444x; 1.0232x over previous
//
#include <hip/hip_runtime.h>
#include <stdint.h>
#include <stddef.h>

// Problem constants
#define BB 2
#define TT 4096
#define EE 768
#define HH 12
#define DH 64
#define WW 256
#define NCHUNK 16
#define GG 16

typedef __bf16 bf16_t;
typedef __bf16 bf16x8 __attribute__((ext_vector_type(8)));
typedef float f32x4 __attribute__((ext_vector_type(4)));

__device__ inline f32x4 mfma16(bf16x8 a, bf16x8 b, f32x4 c) {
    return __builtin_amdgcn_mfma_f32_16x16x32_bf16(a, b, c, 0, 0, 0);
}

__device__ inline void gload16(const void* g, void* l) {
    __builtin_amdgcn_global_load_lds(
        (const __attribute__((address_space(1))) void*)g,
        (__attribute__((address_space(3))) void*)l, 16, 0, 0);
}

// ---------------- prep: x (fp32) -> xb (bf16) ----------------
__global__ __launch_bounds__(256) void k_prep_x(const float* __restrict__ x,
                                                bf16_t* __restrict__ xb) {
    const int i = (blockIdx.x * 256 + threadIdx.x) * 8;
    f32x4 a = *(const f32x4*)(x + i);
    f32x4 b = *(const f32x4*)(x + i + 4);
    bf16x8 o;
    o[0] = (bf16_t)a[0]; o[1] = (bf16_t)a[1]; o[2] = (bf16_t)a[2]; o[3] = (bf16_t)a[3];
    o[4] = (bf16_t)b[0]; o[5] = (bf16_t)b[1]; o[6] = (bf16_t)b[2]; o[7] = (bf16_t)b[3];
    *(bf16x8*)(xb + i) = o;
}

// ---------------- prep: W (fp32, K x N) -> Wt (bf16, N x K), 5 weights ----------------
__global__ __launch_bounds__(256) void k_prep_w(const float* __restrict__ w0,
                                                const float* __restrict__ w1,
                                                const float* __restrict__ w2,
                                                const float* __restrict__ w3,
                                                const float* __restrict__ w4,
                                                bf16_t* __restrict__ wt) {
    const int z = blockIdx.z;
    const float* W = (z == 0) ? w0 : (z == 1) ? w1 : (z == 2) ? w2 : (z == 3) ? w3 : w4;
    const int k0 = blockIdx.x * 64;
    const int n0 = blockIdx.y * 64;
    const int tid = threadIdx.x;
    __shared__ __align__(16) bf16_t ls[64 * 65];
    #pragma unroll
    for (int i = 0; i < 16; ++i) {
        int idx = i * 256 + tid;
        int kr = idx >> 6, nc = idx & 63;
        ls[nc * 65 + kr] = (bf16_t)W[(size_t)(k0 + kr) * EE + n0 + nc];
    }
    __syncthreads();
    bf16_t* o = wt + (size_t)z * EE * EE;
    #pragma unroll
    for (int i = 0; i < 16; ++i) {
        int idx = i * 256 + tid;
        int nr = idx >> 6, kc = idx & 63;
        o[(size_t)(n0 + nr) * EE + k0 + kc] = ls[nr * 65 + kc];
    }
}

// ---------------- projection GEMM: proj[z] = xb @ W[z] + b[z]  (bf16 MFMA) --------------
// m97-style: linear LDS + global_load_lds width-16 staging; LDS-staged coalesced epilogue.
// out layout: (B,H,T,Dh) bf16; z: 0=q(scaled 1/8) 1=k 2=v 3=kgl 4=vgl
__global__ __launch_bounds__(256) void k_gemm(const bf16_t* __restrict__ xb,
                                              const bf16_t* __restrict__ wt,
                                              const float* __restrict__ b0,
                                              const float* __restrict__ b1,
                                              const float* __restrict__ b2,
                                              const float* __restrict__ b3,
                                              const float* __restrict__ b4,
                                              bf16_t* __restrict__ proj) {
    const int tid = threadIdx.x;
    const int z = blockIdx.z;
    const int m0 = blockIdx.x * 128;
    const int n0 = blockIdx.y * 128;
    const float* bias = (z == 0) ? b0 : (z == 1) ? b1 : (z == 2) ? b2 : (z == 3) ? b3 : b4;
    const float scale = (z == 0) ? 0.125f : 1.0f;
    const bf16_t* wz = wt + (size_t)z * EE * EE;
    bf16_t* dst = proj + (size_t)z * BB * HH * TT * DH;

    __shared__ __align__(16) char smem[32768];
    bf16_t* lA = (bf16_t*)smem;             // [128*64]
    bf16_t* lB = (bf16_t*)(smem + 16384);   // [128*64]
    bf16_t* ct = (bf16_t*)smem;             // [128*128] overlay (after K loop)

    const int lane = tid & 63, wid = tid >> 6;
    const int wr = wid >> 1, wc = wid & 1;
    const int lg = lane >> 4, lr = lane & 15;
    const int srow = lane >> 3;        // staging row within 8-row segment
    const int scol = (lane & 7) * 8;   // staging col (elements)

    f32x4 acc[4][4];
    const f32x4 z4 = {0.f, 0.f, 0.f, 0.f};
    #pragma unroll
    for (int i = 0; i < 4; ++i)
        #pragma unroll
        for (int j = 0; j < 4; ++j) acc[i][j] = z4;

    for (int kt = 0; kt < 12; ++kt) {
        const int k0 = kt * 64;
        #pragma unroll
        for (int i = 0; i < 4; ++i) {
            const int seg = wid * 4 + i;             // 0..15, uniform per wave
            const int row = seg * 8 + srow;          // 0..127
            gload16(xb + (size_t)(m0 + row) * EE + k0 + scol, &lA[seg * 512]);
            gload16(wz + (size_t)(n0 + row) * EE + k0 + scol, &lB[seg * 512]);
        }
        __syncthreads();   // drains vmcnt -> LDS staging visible
        #pragma unroll
        for (int kk = 0; kk < 2; ++kk) {
            bf16x8 af[4], bfr[4];
            #pragma unroll
            for (int mi = 0; mi < 4; ++mi)
                af[mi] = *(const bf16x8*)(&lA[(wr * 64 + mi * 16 + lr) * 64 + kk * 32 + lg * 8]);
            #pragma unroll
            for (int ni = 0; ni < 4; ++ni)
                bfr[ni] = *(const bf16x8*)(&lB[(wc * 64 + ni * 16 + lr) * 64 + kk * 32 + lg * 8]);
            #pragma unroll
            for (int mi = 0; mi < 4; ++mi)
                #pragma unroll
                for (int ni = 0; ni < 4; ++ni)
                    acc[mi][ni] = mfma16(af[mi], bfr[ni], acc[mi][ni]);
        }
        __syncthreads();
    }

    // epilogue 1: acc -> bf16 C-tile in LDS (bias+scale applied)
    #pragma unroll
    for (int mi = 0; mi < 4; ++mi)
        #pragma unroll
        for (int ni = 0; ni < 4; ++ni) {
            const int nl = wc * 64 + ni * 16 + lr;
            const float bn = bias[n0 + nl];
            #pragma unroll
            for (int r = 0; r < 4; ++r) {
                const int ml = wr * 64 + mi * 16 + lg * 4 + r;
                ct[ml * 128 + nl] = (bf16_t)((acc[mi][ni][r] + bn) * scale);
            }
        }
    __syncthreads();

    // epilogue 2: coalesced 16B global stores (row of 64 d's = 128B per h)
    #pragma unroll
    for (int it = 0; it < 8; ++it) {
        const int idx = it * 2048 + tid * 8;       // 0..16383
        const int row = idx >> 7, col = idx & 127;
        const int m = m0 + row, n = n0 + col;
        const int h = n >> 6, d = n & 63;
        const int bb = m >> 12, t = m & 4095;
        *(bf16x8*)(dst + (((size_t)bb * HH + h) * TT + t) * DH + d) = *(const bf16x8*)(&ct[idx]);
    }
}

// ---------------- transpose v: (B,H,T,Dh) -> (B,H,Dh,T) bf16 ----------------
__global__ __launch_bounds__(256) void k_tv(const bf16_t* __restrict__ v,
                                            bf16_t* __restrict__ vT) {
    __shared__ __align__(16) bf16_t ls[64 * 65];
    const int t0 = blockIdx.x * 64;
    const int bh = blockIdx.y;
    const int tid = threadIdx.x;
    const bf16_t* vp = v + ((size_t)bh * TT + t0) * DH;
    #pragma unroll
    for (int i = 0; i < 16; ++i) {
        int idx = i * 256 + tid;
        int tr = idx >> 6, dc = idx & 63;
        ls[dc * 65 + tr] = vp[(size_t)tr * DH + dc];
    }
    __syncthreads();
    bf16_t* op = vT + (size_t)bh * DH * TT + t0;
    #pragma unroll
    for (int i = 0; i < 16; ++i) {
        int idx = i * 256 + tid;
        int dr = idx >> 6, tc = idx & 63;
        op[(size_t)dr * TT + tc] = ls[dr * 65 + tc];
    }
}

// ---------------- qg projection: qg = (x[global] @ Wqg + bqg) * 1/8, fp32 ----------------
// out: (B,H,G,Dh) fp32
__global__ __launch_bounds__(256) void k_qg(const float* __restrict__ x,
                                            const float* __restrict__ Wqg,
                                            const float* __restrict__ bqg,
                                            float* __restrict__ qg) {
    const int g = blockIdx.x, b = blockIdx.y;
    const int tid = threadIdx.x;
    __shared__ float xr[EE];
    const float* xrow = x + ((size_t)b * TT + g * WW) * EE;
    for (int i = tid; i < EE; i += 256) xr[i] = xrow[i];
    __syncthreads();
    float a0 = bqg[tid], a1 = bqg[tid + 256], a2 = bqg[tid + 512];
    for (int e = 0; e < EE; ++e) {
        float xe = xr[e];
        const float* wrow = Wqg + (size_t)e * EE;
        a0 += xe * wrow[tid];
        a1 += xe * wrow[tid + 256];
        a2 += xe * wrow[tid + 512];
    }
    float accs[3] = {a0, a1, a2};
    #pragma unroll
    for (int j = 0; j < 3; ++j) {
        int n = tid + j * 256;
        int h = n >> 6, d = n & 63;
        qg[(((size_t)b * HH + h) * GG + g) * DH + d] = accs[j] * 0.125f;
    }
}

// ---------------- local (windowed + global-col) attention ----------------
// v6: split-K 2 waves (as v5) + EARLY V-tile loads: V dwordx4s issued right after
// K fragment loads (before softmax), so V latency hides under QK^T+softmax instead
// of sitting exposed after the sched_barrier. +32 VGPR, accepted.
__global__ __launch_bounds__(128) void k_lattn(const bf16_t* __restrict__ qs,
                                               const bf16_t* __restrict__ ks,
                                               const bf16_t* __restrict__ vT,
                                               float* __restrict__ out) {
    const int gx0 = blockIdx.x;
    const int gx = (gx0 & 7) * 192 + (gx0 >> 3);   // 3 consecutive bh per XCD
    const int q4 = gx & 3;
    const int c = (gx >> 2) & 15;
    const int bh = gx >> 6;          // 0..23
    const int b = bh / HH, h = bh % HH;
    const int tid = threadIdx.x;
    const int w = tid >> 6;          // wave id 0/1
    const int lane = tid & 63, lg = lane >> 4, lr = lane & 15;

    const bf16_t* qp = qs + ((size_t)bh * TT + c * WW + q4 * 64) * DH;
    const bf16_t* kp = ks + (size_t)bh * TT * DH;
    const bf16_t* vp = vT + (size_t)bh * DH * TT;

    __shared__ __align__(16) char smem[26880];
    bf16_t* Pw  = (bf16_t*)(smem + (size_t)w * 9216);
    bf16_t* Kg  = (bf16_t*)(smem + 18432);
    bf16_t* VgT = (bf16_t*)(smem + 20736);
    float*  Om  = (float*)smem;
    float*  ml  = (float*)(smem + 25856);   // [w][{m,l}][64]

    if (w == 0) {
        // stage global K rows (16 x 64, vectorized)
        #pragma unroll
        for (int i = 0; i < 2; ++i) {
            int idx = i * 64 + lane;          // 0..127
            int r = idx >> 3, d8 = (idx & 7) * 8;
            *(bf16x8*)(&Kg[r * 72 + d8]) = *(const bf16x8*)(kp + (size_t)r * WW * DH + d8);
        }
        // stage global V^T (d-major, zero-padded cols 16..31)
        #pragma unroll
        for (int g = 0; g < 32; ++g)
            VgT[lane * 40 + g] = (g < 16) ? vp[(size_t)lane * TT + g * WW] : (bf16_t)0.f;
    }

    // Q fragments (A operand): row = lr (+16*mi), k = lg*8 (+32*kk)
    bf16x8 Qf[4][2];
    #pragma unroll
    for (int mi = 0; mi < 4; ++mi)
        #pragma unroll
        for (int kk = 0; kk < 2; ++kk)
            Qf[mi][kk] = *(const bf16x8*)(qp + (size_t)(mi * 16 + lr) * DH + kk * 32 + lg * 8);

    f32x4 O[4][4];
    const f32x4 z4 = {0.f, 0.f, 0.f, 0.f};
    #pragma unroll
    for (int i = 0; i < 4; ++i)
        #pragma unroll
        for (int j = 0; j < 4; ++j) O[i][j] = z4;

    float m_own[16], l_own[16];
    #pragma unroll
    for (int i = 0; i < 16; ++i) { m_own[i] = -1e30f; l_own[i] = 0.f; }

    __syncthreads();   // staging visible to both waves

    for (int ts = w; ts < 10; ts += 2) {
        const bool isg = (ts == 0);
        const int jt = q4 + ts - 1;
        const int ttile = 4 * (c - 1) + jt;   // global 64-key tile index
        if (!isg && (ttile < 0 || ttile > 63)) continue;
        const bool gdrop = !isg && ((jt & 3) == 0);

        // K fragments (B operand): col = key, k = d
        bf16x8 kf[4][2];
        // V fragments for this tile, issued EARLY (latency hides under QK+softmax)
        bf16x8 vfr[2][4];
        if (isg) {
            #pragma unroll
            for (int kk = 0; kk < 2; ++kk)
                kf[0][kk] = *(const bf16x8*)(&Kg[lr * 72 + kk * 32 + lg * 8]);
            #pragma unroll
            for (int di = 0; di < 4; ++di)
                vfr[0][di] = *(const bf16x8*)(&VgT[(di * 16 + lr) * 40 + lg * 8]);
        } else {
            const bf16_t* ktp = kp + (size_t)ttile * 64 * DH;
            #pragma unroll
            for (int ni = 0; ni < 4; ++ni)
                #pragma unroll
                for (int kk = 0; kk < 2; ++kk)
                    kf[ni][kk] = *(const bf16x8*)(ktp + (size_t)(ni * 16 + lr) * DH + kk * 32 + lg * 8);
            #pragma unroll
            for (int kkp = 0; kkp < 2; ++kkp)
                #pragma unroll
                for (int di = 0; di < 4; ++di)
                    vfr[kkp][di] = *(const bf16x8*)(vp + (size_t)(di * 16 + lr) * TT + ttile * 64 + kkp * 32 + lg * 8);
        }

        #pragma unroll
        for (int mi = 0; mi < 4; ++mi) {
            f32x4 S[4] = {z4, z4, z4, z4};
            if (isg) {
                #pragma unroll
                for (int kk = 0; kk < 2; ++kk)
                    S[0] = mfma16(Qf[mi][kk], kf[0][kk], S[0]);
            } else {
                #pragma unroll
                for (int kk = 0; kk < 2; ++kk)
                    #pragma unroll
                    for (int ni = 0; ni < 4; ++ni)
                        S[ni] = mfma16(Qf[mi][kk], kf[ni][kk], S[ni]);
            }

            // wave-parallel online softmax on C layout: row = mi*16+lg*4+r, col = ni*16+lr
            #pragma unroll
            for (int r = 0; r < 4; ++r) {
                const int row = mi * 16 + lg * 4 + r;
                const int idx = mi * 4 + r;
                float sv[4];
                #pragma unroll
                for (int ni = 0; ni < 4; ++ni) {
                    const int cc = ni * 16 + lr;
                    bool ok = isg ? (ni == 0)
                                  : !((ts == 1 && cc < row) || (ts == 9 && cc > row) ||
                                      (gdrop && cc == 0));
                    sv[ni] = ok ? S[ni][r] : -1e30f;
                }
                float tmax = fmaxf(fmaxf(sv[0], sv[1]), fmaxf(sv[2], sv[3]));
                tmax = fmaxf(tmax, __shfl_xor(tmax, 1));
                tmax = fmaxf(tmax, __shfl_xor(tmax, 2));
                tmax = fmaxf(tmax, __shfl_xor(tmax, 4));
                tmax = fmaxf(tmax, __shfl_xor(tmax, 8));
                const float m2 = fmaxf(m_own[idx], tmax);
                const float scr = __expf(m_own[idx] - m2);
                float rs = 0.f;
                #pragma unroll
                for (int ni = 0; ni < 4; ++ni) {
                    float p = __expf(sv[ni] - m2);   // masked -> underflow to 0
                    rs += p;
                    Pw[row * 72 + ni * 16 + lr] = (bf16_t)p;
                }
                rs += __shfl_xor(rs, 1);
                rs += __shfl_xor(rs, 2);
                rs += __shfl_xor(rs, 4);
                rs += __shfl_xor(rs, 8);
                m_own[idx] = m2;
                l_own[idx] = l_own[idx] * scr + rs;
                #pragma unroll
                for (int di = 0; di < 4; ++di) O[mi][di][r] *= scr;
            }
        }

        // wait for own-wave P ds_writes before cross-lane P reads; pin ordering.
        asm volatile("s_waitcnt lgkmcnt(0)" ::: "memory");
        __builtin_amdgcn_sched_barrier(0);

        // PV: A = P (rows=q, k=key), B = V^T fragments already in registers
        #pragma unroll
        for (int kkp = 0; kkp < 2; ++kkp) {
            if (isg && kkp == 1) continue;   // global-tile keys 32..63 have P==0
            bf16x8 pa[4];
            #pragma unroll
            for (int mi = 0; mi < 4; ++mi)
                pa[mi] = *(const bf16x8*)(&Pw[(mi * 16 + lr) * 72 + kkp * 32 + lg * 8]);
            #pragma unroll
            for (int di = 0; di < 4; ++di) {
                #pragma unroll
                for (int mi = 0; mi < 4; ++mi) O[mi][di] = mfma16(pa[mi], vfr[kkp][di], O[mi][di]);
            }
        }
    }

    __syncthreads();   // both waves' tile loops done; P buffers dead -> Om overlay OK

    // publish per-wave m, l
    #pragma unroll
    for (int mi = 0; mi < 4; ++mi)
        #pragma unroll
        for (int r = 0; r < 4; ++r)
            if (lr == 0) {
                int row = mi * 16 + lg * 4 + r;
                ml[w * 128 + row]      = m_own[mi * 4 + r];
                ml[w * 128 + 64 + row] = l_own[mi * 4 + r];
            }
    __syncthreads();

    if (w == 1) {
        #pragma unroll
        for (int mi = 0; mi < 4; ++mi)
            #pragma unroll
            for (int r = 0; r < 4; ++r) {
                const int row = mi * 16 + lg * 4 + r;
                const int idx = mi * 4 + r;
                const float mstar = fmaxf(ml[row], m_own[idx]);
                const float s1 = __expf(m_own[idx] - mstar);
                #pragma unroll
                for (int di = 0; di < 4; ++di)
                    Om[row * 64 + di * 16 + lr] = O[mi][di][r] * s1;
                if (lr == 0) ml[128 + 64 + row] = l_own[idx] * s1;   // scaled l1
            }
    }
    __syncthreads();

    if (w == 0) {
        const size_t outbase = ((size_t)b * TT + c * WW + q4 * 64) * EE + h * DH;
        #pragma unroll
        for (int mi = 0; mi < 4; ++mi)
            #pragma unroll
            for (int r = 0; r < 4; ++r) {
                const int row = mi * 16 + lg * 4 + r;
                const int idx = mi * 4 + r;
                const float m1 = ml[128 + row];
                const float mstar = fmaxf(m_own[idx], m1);
                const float s0 = __expf(m_own[idx] - mstar);
                const float l = l_own[idx] * s0 + ml[128 + 64 + row];
                const float linv = 1.f / l;
                #pragma unroll
                for (int di = 0; di < 4; ++di)
                    out[outbase + (size_t)row * EE + di * 16 + lr] =
                        (O[mi][di][r] * s0 + Om[row * 64 + di * 16 + lr]) * linv;
            }
    }
}

// ---------------- global-token attention: rows t=256g, full softmax over T -------------
__global__ __launch_bounds__(256) void k_gattn(const float* __restrict__ qg,
                                               const bf16_t* __restrict__ kgl,
                                               const bf16_t* __restrict__ vgl,
                                               float* __restrict__ out) {
    const int gx = blockIdx.x;
    const int g = gx & 15;
    const int bh = gx >> 4;
    const int b = bh / HH, h = bh % HH;
    const int tid = threadIdx.x;
    const int lane = tid & 63, w = tid >> 6;

    __shared__ float qrow[DH];
    __shared__ float sc[TT];
    __shared__ float red[256];

    if (tid < DH) qrow[tid] = qg[(((size_t)bh) * GG + g) * DH + tid];
    __syncthreads();

    const bf16_t* kp = kgl + (size_t)bh * TT * DH;
    float lmax = -1e30f;
    for (int t = tid; t < TT; t += 256) {
        const bf16_t* kr = kp + (size_t)t * DH;
        float s = 0.f;
        #pragma unroll
        for (int d0 = 0; d0 < DH; d0 += 8) {
            bf16x8 kv = *(const bf16x8*)(kr + d0);
            #pragma unroll
            for (int jj = 0; jj < 8; ++jj) s += qrow[d0 + jj] * (float)kv[jj];
        }
        sc[t] = s;
        lmax = fmaxf(lmax, s);
    }
    #pragma unroll
    for (int off = 32; off; off >>= 1) lmax = fmaxf(lmax, __shfl_xor(lmax, off));
    if (lane == 0) red[w] = lmax;
    __syncthreads();
    const float M = fmaxf(fmaxf(red[0], red[1]), fmaxf(red[2], red[3]));
    float lsum = 0.f;
    for (int t = tid; t < TT; t += 256) {
        float p = __expf(sc[t] - M);
        sc[t] = p;
        lsum += p;
    }
    #pragma unroll
    for (int off = 32; off; off >>= 1) lsum += __shfl_xor(lsum, off);
    __syncthreads();                 // red[0..3] reads done
    if (lane == 0) red[64 + w] = lsum;
    __syncthreads();
    const float SUM = red[64] + red[65] + red[66] + red[67];
    __syncthreads();                 // everyone has SUM before red reuse

    const bf16_t* vp = vgl + (size_t)bh * TT * DH;
    float a0 = 0.f, a1 = 0.f, a2 = 0.f, a3 = 0.f;
    const int tbase = w * 1024;
    for (int t = tbase; t < tbase + 1024; t += 4) {
        a0 += sc[t] * (float)vp[(size_t)t * DH + lane];
        a1 += sc[t + 1] * (float)vp[(size_t)(t + 1) * DH + lane];
        a2 += sc[t + 2] * (float)vp[(size_t)(t + 2) * DH + lane];
        a3 += sc[t + 3] * (float)vp[(size_t)(t + 3) * DH + lane];
    }
    red[tid] = (a0 + a1) + (a2 + a3);
    __syncthreads();
    if (w == 0) {
        float tot = red[lane] + red[64 + lane] + red[128 + lane] + red[192 + lane];
        out[((size_t)b * TT + g * WW) * EE + h * DH + lane] = tot / SUM;
    }
}

// ---------------- launch ----------------
extern "C" void kernel_launch(void* const* d_in, const int* in_sizes, int n_in,
                              void* d_out, int out_size, void* d_ws, size_t ws_size,
                              hipStream_t stream) {
    const float* x   = (const float*)d_in[0];
    const float* Wq  = (const float*)d_in[1];
    const float* bq  = (const float*)d_in[2];
    const float* Wk  = (const float*)d_in[3];
    const float* bk  = (const float*)d_in[4];
    const float* Wv  = (const float*)d_in[5];
    const float* bv  = (const float*)d_in[6];
    const float* Wqg = (const float*)d_in[7];
    const float* bqg = (const float*)d_in[8];
    const float* Wkg = (const float*)d_in[9];
    const float* bkg = (const float*)d_in[10];
    const float* Wvg = (const float*)d_in[11];
    const float* bvg = (const float*)d_in[12];
    float* out = (float*)d_out;

    const size_t NX = (size_t)BB * TT * EE;          // 6,291,456
    const size_t NW = (size_t)EE * EE;               // 589,824
    const size_t NP = (size_t)BB * HH * TT * DH;     // 6,291,456

    bf16_t* xb   = (bf16_t*)d_ws;
    bf16_t* wt   = xb + NX;
    bf16_t* proj = wt + 5 * NW;
    bf16_t* vT   = proj + 5 * NP;
    float*  qg   = (float*)(vT + NP);

    (void)bvg; (void)in_sizes; (void)n_in; (void)out_size; (void)ws_size;

    k_prep_x<<<dim3((unsigned)(NX / (256 * 8))), 256, 0, stream>>>(x, xb);
    k_prep_w<<<dim3(12, 12, 5), 256, 0, stream>>>(Wq, Wk, Wv, Wkg, Wvg, wt);
    k_gemm<<<dim3(64, 6, 5), 256, 0, stream>>>(xb, wt, bq, bk, bv, bkg, bvg, proj);
    k_tv<<<dim3(64, 24), 256, 0, stream>>>(proj + 2 * NP, vT);
    k_qg<<<dim3(16, 2), 256, 0, stream>>>(x, Wqg, bqg, qg);
    k_lattn<<<dim3(1536), 128, 0, stream>>>(proj, proj + NP, vT, out);
    k_gattn<<<dim3(384), 256, 0, stream>>>(qg, proj + 3 * NP, proj + 4 * NP, out);
}